// Round 8
// baseline (449.923 us; speedup 1.0000x reference)
//
#include <hip/hip_runtime.h>
#include <hip/hip_bf16.h>

#define N_NODES 50000
#define N_EDGES 800000
#define IN_DIM 128
#define HID_DIM 256
#define OUT_DIM 40
#define M_PAD 50048      // 782 * 64
#define SCAN_BLOCKS 196  // 196*256 = 50176 >= 50000
#define NBUCKETS 782     // 64 nodes per bucket
#define BCAP 1536        // mean 1023 + 16 sigma

// ---- workspace layout (bytes) ----
#define OFF_CNT   0          // 50000 int
#define OFF_BCUR  200000     // 782 int  (zeroed together with cnt)
#define ZERO_BYTES 203128
#define OFF_RP    203136     // 50001 int row_ptr
#define OFF_ESRC  403152     // 800000 int
#define OFF_STAGE 3603152    // 782*1536 int2 = 9609216
#define OFF_AB    13212368   // M_PAD x 256 bf16 (cols 0-127 agg1, 128-255 x)
#define OFF_H     38836944   // M_PAD x 256 bf16
#define OFF_W1T   64461520   // 256 x 256 bf16
#define OFF_W2T   64592592   // 80 x 256 bf16
#define OFF_P2    64633552   // M_PAD x 40 bf16
#define OFF_R2    68637392   // M_PAD x 40 f32
#define OFF_BSUM  76645072   // 256 int
#define OFF_BOFF  76646096   // 256 int
// end ~76.65 MB

typedef __attribute__((ext_vector_type(8))) short short8;
typedef __attribute__((ext_vector_type(4))) float f32x4;

__device__ __forceinline__ float bfu2f(unsigned u) {
  union { unsigned i; float f; } c; c.i = u << 16; return c.f;
}
__device__ __forceinline__ unsigned f2bfu(float f) {
  union { float f; unsigned i; } c; c.f = f;
  return (c.i + 0x7fffu + ((c.i >> 16) & 1u)) >> 16;   // RNE
}

#define GLOAD_LDS16(g, l)                                                      \
  __builtin_amdgcn_global_load_lds(                                            \
      (const __attribute__((address_space(1))) void*)(g),                      \
      (__attribute__((address_space(3))) void*)(l), 16, 0, 0)

// ---------------- CSR build (bucketed counting sort) ----------------
// one pass: node histogram + bucket-sequential stage of (src,dst)
__global__ void k_bfill(const int* __restrict__ src, const int* __restrict__ dst,
                        int* __restrict__ cnt, int* __restrict__ bcur,
                        int2* __restrict__ stage) {
  int e = blockIdx.x * blockDim.x + threadIdx.x;
  if (e >= N_EDGES) return;
  int d = dst[e];
  atomicAdd(&cnt[d], 1);
  int b = d >> 6;
  int pos = atomicAdd(&bcur[b], 1);
  stage[(size_t)b * BCAP + pos] = make_int2(src[e], d);
}

__global__ __launch_bounds__(256) void k_scanA(const int* __restrict__ cnt,
                                               int* __restrict__ bsum) {
  __shared__ int red[256];
  int t = threadIdx.x;
  int node = blockIdx.x * 256 + t;
  red[t] = (node < N_NODES) ? cnt[node] : 0;
  __syncthreads();
  for (int off = 128; off; off >>= 1) {
    if (t < off) red[t] += red[t + off];
    __syncthreads();
  }
  if (t == 0) bsum[blockIdx.x] = red[0];
}

__global__ __launch_bounds__(256) void k_scanB(const int* __restrict__ bsum,
                                               int* __restrict__ boff,
                                               int* __restrict__ row_ptr) {
  __shared__ int part[256];
  int t = threadIdx.x;
  int v = (t < SCAN_BLOCKS) ? bsum[t] : 0;
  part[t] = v;
  __syncthreads();
  for (int off = 1; off < 256; off <<= 1) {
    int u = (t >= off) ? part[t - off] : 0;
    __syncthreads();
    part[t] += u;
    __syncthreads();
  }
  if (t < SCAN_BLOCKS) boff[t] = part[t] - v;
  if (t == 255) row_ptr[N_NODES] = part[255];
}

__global__ __launch_bounds__(256) void k_scanC(const int* __restrict__ cnt,
                                               const int* __restrict__ boff,
                                               int* __restrict__ row_ptr) {
  __shared__ int part[256];
  int t = threadIdx.x;
  int node = blockIdx.x * 256 + t;
  int v = (node < N_NODES) ? cnt[node] : 0;
  part[t] = v;
  __syncthreads();
  for (int off = 1; off < 256; off <<= 1) {
    int u = (t >= off) ? part[t - off] : 0;
    __syncthreads();
    part[t] += u;
    __syncthreads();
  }
  if (node < N_NODES) row_ptr[node] = boff[blockIdx.x] + part[t] - v;
}

// per bucket: LDS scatter to node order, coalesced esrc write
__global__ __launch_bounds__(256) void k_bsort(const int2* __restrict__ stage,
                                               const int* __restrict__ bcur,
                                               const int* __restrict__ row_ptr,
                                               int* __restrict__ esrc) {
  __shared__ int lcur[64];
  __shared__ int lout[BCAP];
  int b = blockIdx.x;
  int t = threadIdx.x;
  int n0 = b * 64;
  int base = row_ptr[min(n0, N_NODES)];
  if (t < 64) {
    int idx = min(n0 + t, N_NODES);
    lcur[t] = row_ptr[idx] - base;
  }
  __syncthreads();
  int nb = bcur[b];
  const int2* sp = stage + (size_t)b * BCAP;
  for (int e = t; e < nb; e += 256) {
    int2 p = sp[e];
    int lp = atomicAdd(&lcur[p.y - n0], 1);
    lout[lp] = p.x;
  }
  __syncthreads();
  for (int i = t; i < nb; i += 256) esrc[base + i] = lout[i];
}

// ---------------- conversions ----------------
__global__ __launch_bounds__(256) void k_convx(const float* __restrict__ x,
                                               char* __restrict__ ABb) {
  int t = blockIdx.x * 256 + threadIdx.x;
  int row = t >> 4, c8 = (t & 15) << 3;
  if (row >= N_NODES) return;
  const float* xp = x + (size_t)row * IN_DIM + c8;
  unsigned short o[8];
#pragma unroll
  for (int i = 0; i < 8; ++i) o[i] = (unsigned short)f2bfu(xp[i]);
  *(short8*)(ABb + (size_t)row * 512 + 256 + c8 * 2) = *(short8*)o;
}

__global__ __launch_bounds__(256) void k_convw1(const float* __restrict__ W1l,
                                                const float* __restrict__ W1r,
                                                unsigned short* __restrict__ Wt1) {
  int n = blockIdx.x, k = threadIdx.x;
  float v = (k < 128) ? W1l[(size_t)k * HID_DIM + n]
                      : W1r[(size_t)(k - 128) * HID_DIM + n];
  Wt1[(size_t)n * 256 + k] = (unsigned short)f2bfu(v);
}

__global__ __launch_bounds__(256) void k_convw2(const float* __restrict__ W2l,
                                                const float* __restrict__ W2r,
                                                unsigned short* __restrict__ Wt2) {
  int n = blockIdx.x, k = threadIdx.x;
  float v = (n < OUT_DIM) ? W2l[(size_t)k * OUT_DIM + n]
                          : W2r[(size_t)k * OUT_DIM + (n - OUT_DIM)];
  Wt2[(size_t)n * 256 + k] = (unsigned short)f2bfu(v);
}

// ---------------- aggregation 1 (bf16 gather, mean) ----------------
__global__ __launch_bounds__(256) void k_agg1(char* __restrict__ ABb,
    const int* __restrict__ row_ptr, const int* __restrict__ esrc) {
  int tid = threadIdx.x;
  int node = blockIdx.x * 4 + (tid >> 6);
  int lane = tid & 63;
  int g = lane >> 4;        // 0..3 edge subgroup
  int q = lane & 15;        // channel slot: ch q*8..q*8+7
  int beg = row_ptr[node], end = row_ptr[node + 1];
  float s[8];
#pragma unroll
  for (int j = 0; j < 8; ++j) s[j] = 0.f;

  for (int e0 = beg; e0 < end; e0 += 4) {
    int e = e0 + g;
    if (e < end) {
      int srcn = esrc[e];
      short8 v = *(const short8*)(ABb + (size_t)srcn * 512 + 256 + q * 16);
#pragma unroll
      for (int j = 0; j < 8; ++j)
        s[j] += bfu2f((unsigned short)v[j]);
    }
  }
#pragma unroll
  for (int j = 0; j < 8; ++j) {
    s[j] += __shfl_xor(s[j], 16, 64);
    s[j] += __shfl_xor(s[j], 32, 64);
  }
  float inv = 1.0f / (float)max(end - beg, 1);
  if (lane < 16) {
    unsigned short o[8];
#pragma unroll
    for (int j = 0; j < 8; ++j) o[j] = (unsigned short)f2bfu(s[j] * inv);
    *(short8*)(ABb + (size_t)node * 512 + q * 16) = *(short8*)o;
  }
}

// ---------------- GEMM1: H = relu(AB @ W1cat + b1), bf16 MFMA ----------------
__global__ __launch_bounds__(256) void k_gemm1(
    const char* __restrict__ ABb, const short* __restrict__ Wt1,
    const float* __restrict__ b1, unsigned short* __restrict__ H) {
  __shared__ __align__(16) char As[64 * 512];
  const int tid = threadIdx.x;
  const int w = tid >> 6, lane = tid & 63;
  const int row0 = blockIdx.x * 64;

  {
    const char* gbase = ABb + (size_t)row0 * 512;
#pragma unroll
    for (int i = 0; i < 8; ++i) {
      int o = i * 4096 + w * 1024 + lane * 16;
      int row = o >> 9;
      int kslot = ((o & 511) >> 4) ^ (row & 7);
      GLOAD_LDS16(gbase + row * 512 + kslot * 16, As + i * 4096 + w * 1024);
    }
  }
  __syncthreads();

  f32x4 acc[4][4];
#pragma unroll
  for (int mi = 0; mi < 4; ++mi)
#pragma unroll
    for (int ni = 0; ni < 4; ++ni) acc[mi][ni] = (f32x4){0.f, 0.f, 0.f, 0.f};

  const short* wb = Wt1 + (size_t)(w * 64 + (lane & 15)) * 256 + (lane >> 4) * 8;

  for (int ks = 0; ks < 8; ++ks) {
    short8 af[4], bf[4];
#pragma unroll
    for (int mi = 0; mi < 4; ++mi) {
      int row = mi * 16 + (lane & 15);
      int kslot = (ks * 4 + (lane >> 4)) ^ (row & 7);
      af[mi] = *(const short8*)(As + row * 512 + kslot * 16);
    }
#pragma unroll
    for (int ni = 0; ni < 4; ++ni)
      bf[ni] = *(const short8*)(wb + ni * 16 * 256 + ks * 32);
#pragma unroll
    for (int mi = 0; mi < 4; ++mi)
#pragma unroll
      for (int ni = 0; ni < 4; ++ni)
        acc[mi][ni] = __builtin_amdgcn_mfma_f32_16x16x32_bf16(
            af[mi], bf[ni], acc[mi][ni], 0, 0, 0);
  }

#pragma unroll
  for (int ni = 0; ni < 4; ++ni) {
    int col = w * 64 + ni * 16 + (lane & 15);
    float bv = b1[col];
#pragma unroll
    for (int mi = 0; mi < 4; ++mi) {
      int rbase = row0 + mi * 16 + (lane >> 4) * 4;
#pragma unroll
      for (int r = 0; r < 4; ++r) {
        float v = fmaxf(acc[mi][ni][r] + bv, 0.f);
        H[(size_t)(rbase + r) * 256 + col] = (unsigned short)f2bfu(v);
      }
    }
  }
}

// ---------------- GEMM2: [p2|r2] = H @ W2cat (+b2 on r2), bf16 MFMA ----------
__global__ __launch_bounds__(256) void k_gemm2(
    const char* __restrict__ Hb, const short* __restrict__ Wt2,
    const float* __restrict__ b2, unsigned short* __restrict__ P2,
    float* __restrict__ R2) {
  __shared__ __align__(16) char As[64 * 512];
  const int tid = threadIdx.x;
  const int w = tid >> 6, lane = tid & 63;
  const int row0 = blockIdx.x * 64;

  {
    const char* gbase = Hb + (size_t)row0 * 512;
#pragma unroll
    for (int i = 0; i < 8; ++i) {
      int o = i * 4096 + w * 1024 + lane * 16;
      int row = o >> 9;
      int kslot = ((o & 511) >> 4) ^ (row & 7);
      GLOAD_LDS16(gbase + row * 512 + kslot * 16, As + i * 4096 + w * 1024);
    }
  }
  __syncthreads();

  f32x4 acc[5];
#pragma unroll
  for (int ni = 0; ni < 5; ++ni) acc[ni] = (f32x4){0.f, 0.f, 0.f, 0.f};

  const short* wb = Wt2 + (size_t)(lane & 15) * 256 + (lane >> 4) * 8;
  const int arow = w * 16 + (lane & 15);

  for (int ks = 0; ks < 8; ++ks) {
    int kslot = (ks * 4 + (lane >> 4)) ^ (arow & 7);
    short8 a = *(const short8*)(As + arow * 512 + kslot * 16);
#pragma unroll
    for (int ni = 0; ni < 5; ++ni) {
      short8 bf = *(const short8*)(wb + ni * 16 * 256 + ks * 32);
      acc[ni] = __builtin_amdgcn_mfma_f32_16x16x32_bf16(a, bf, acc[ni], 0, 0, 0);
    }
  }

#pragma unroll
  for (int ni = 0; ni < 5; ++ni) {
    int col = ni * 16 + (lane & 15);
#pragma unroll
    for (int r = 0; r < 4; ++r) {
      int row = row0 + w * 16 + (lane >> 4) * 4 + r;
      float v = acc[ni][r];
      if (col < OUT_DIM) {
        P2[(size_t)row * OUT_DIM + col] = (unsigned short)f2bfu(v);
      } else {
        R2[(size_t)row * OUT_DIM + (col - OUT_DIM)] = v + b2[col - OUT_DIM];
      }
    }
  }
}

// ---------------- agg2 + log_softmax ----------------
__global__ __launch_bounds__(256) void k_agg2(const unsigned short* __restrict__ P2,
    const float* __restrict__ R2, const int* __restrict__ row_ptr,
    const int* __restrict__ esrc, float* __restrict__ out) {
  int tid = threadIdx.x;
  int node = blockIdx.x * 4 + (tid >> 6);
  int lane = tid & 63;
  int g = lane >> 3;        // 0..7 edge slot
  int q = lane & 7;         // 0..4 active: channels q*8..q*8+7
  int beg = row_ptr[node], end = row_ptr[node + 1];
  float s[8];
#pragma unroll
  for (int j = 0; j < 8; ++j) s[j] = 0.f;

  for (int e0 = beg; e0 < end; e0 += 8) {
    int e = e0 + g;
    if (e < end && q < 5) {
      int srcn = esrc[e];
      short8 v = *(const short8*)((const char*)P2 + (size_t)srcn * 80 + q * 16);
#pragma unroll
      for (int j = 0; j < 8; ++j)
        s[j] += bfu2f((unsigned short)v[j]);
    }
  }
#pragma unroll
  for (int j = 0; j < 8; ++j) {
    s[j] += __shfl_xor(s[j], 8, 64);
    s[j] += __shfl_xor(s[j], 16, 64);
    s[j] += __shfl_xor(s[j], 32, 64);
  }

  float inv = 1.0f / (float)max(end - beg, 1);
  float v[8];
  float m = -1e30f;
  if (q < 5) {
    const float* rr = R2 + (size_t)node * OUT_DIM + q * 8;
    f32x4 r0 = *(const f32x4*)rr;
    f32x4 r1 = *(const f32x4*)(rr + 4);
#pragma unroll
    for (int j = 0; j < 8; ++j) {
      float rj = (j < 4) ? r0[j] : r1[j - 4];
      v[j] = s[j] * inv + rj;
      m = fmaxf(m, v[j]);
    }
  }
#pragma unroll
  for (int o = 1; o <= 4; o <<= 1) m = fmaxf(m, __shfl_xor(m, o, 64));
  float ex = 0.f;
  if (q < 5) {
#pragma unroll
    for (int j = 0; j < 8; ++j) ex += __expf(v[j] - m);
  }
#pragma unroll
  for (int o = 1; o <= 4; o <<= 1) ex += __shfl_xor(ex, o, 64);
  float ls = __logf(ex) + m;

  if (g == 0 && q < 5) {
    float* op = out + (size_t)node * OUT_DIM + q * 8;
    f32x4 o0, o1;
#pragma unroll
    for (int j = 0; j < 4; ++j) { o0[j] = v[j] - ls; o1[j] = v[j + 4] - ls; }
    *(f32x4*)op = o0;
    *(f32x4*)(op + 4) = o1;
  }
}

extern "C" void kernel_launch(void* const* d_in, const int* in_sizes, int n_in,
                              void* d_out, int out_size, void* d_ws, size_t ws_size,
                              hipStream_t stream) {
  const float* x   = (const float*)d_in[0];
  const int*   ei  = (const int*)d_in[1];
  const float* W1l = (const float*)d_in[2];
  const float* W1r = (const float*)d_in[3];
  const float* b1  = (const float*)d_in[4];
  const float* W2l = (const float*)d_in[5];
  const float* W2r = (const float*)d_in[6];
  const float* b2  = (const float*)d_in[7];
  float* out = (float*)d_out;

  const int* src = ei;
  const int* dst = ei + N_EDGES;

  char* ws = (char*)d_ws;
  int*   cnt     = (int*)(ws + OFF_CNT);
  int*   bcur    = (int*)(ws + OFF_BCUR);
  int*   row_ptr = (int*)(ws + OFF_RP);
  int*   esrc    = (int*)(ws + OFF_ESRC);
  int2*  stage   = (int2*)(ws + OFF_STAGE);
  char*  ABb     = ws + OFF_AB;
  char*  Hb      = ws + OFF_H;
  unsigned short* Wt1 = (unsigned short*)(ws + OFF_W1T);
  unsigned short* Wt2 = (unsigned short*)(ws + OFF_W2T);
  unsigned short* P2  = (unsigned short*)(ws + OFF_P2);
  float* R2   = (float*)(ws + OFF_R2);
  int*   bsum = (int*)(ws + OFF_BSUM);
  int*   boff = (int*)(ws + OFF_BOFF);

  (void)hipMemsetAsync(ws, 0, ZERO_BYTES, stream);   // cnt + bcur
  (void)hipMemsetAsync(ABb + (size_t)N_NODES * 512, 0, (M_PAD - N_NODES) * 512,
                       stream);

  k_convx<<<(N_NODES * 16 + 255) / 256, 256, 0, stream>>>(x, ABb);
  k_convw1<<<256, 256, 0, stream>>>(W1l, W1r, Wt1);
  k_convw2<<<80, 256, 0, stream>>>(W2l, W2r, Wt2);

  k_bfill<<<(N_EDGES + 255) / 256, 256, 0, stream>>>(src, dst, cnt, bcur, stage);
  k_scanA<<<SCAN_BLOCKS, 256, 0, stream>>>(cnt, bsum);
  k_scanB<<<1, 256, 0, stream>>>(bsum, boff, row_ptr);
  k_scanC<<<SCAN_BLOCKS, 256, 0, stream>>>(cnt, boff, row_ptr);
  k_bsort<<<NBUCKETS, 256, 0, stream>>>(stage, bcur, row_ptr, esrc);

  k_agg1<<<N_NODES / 4, 256, 0, stream>>>(ABb, row_ptr, esrc);
  k_gemm1<<<M_PAD / 64, 256, 0, stream>>>(ABb, (const short*)Wt1, b1,
                                          (unsigned short*)Hb);
  k_gemm2<<<M_PAD / 64, 256, 0, stream>>>(Hb, (const short*)Wt2, b2, P2, R2);
  k_agg2<<<N_NODES / 4, 256, 0, stream>>>(P2, R2, row_ptr, esrc, out);
}

// Round 10
// 285.243 us; speedup vs baseline: 1.5773x; 1.5773x over previous
//
#include <hip/hip_runtime.h>
#include <hip/hip_bf16.h>

#define N_NODES 50000
#define N_EDGES 800000
#define IN_DIM 128
#define HID_DIM 256
#define OUT_DIM 40
#define M_PAD 50048      // 782 * 64
#define SCAN_BLOCKS 196  // 196*256 = 50176 >= 50000
#define NBUCKETS 782     // 64 nodes per bucket
#define BCAP 1536        // mean 1024 + 16 sigma
#define EPB 8192         // edges per binning block
#define BINA_BLOCKS 98   // ceil(800000/8192)

// ---- workspace layout (bytes), all 16-B aligned ----
#define OFF_CNT   0          // 50000 int
#define OFF_BCUR  200000     // 782 int (zeroed with cnt)
#define ZERO_BYTES 203128
#define OFF_RP    203136     // 50001 int row_ptr
#define OFF_ESRC  403152     // 800000 int
#define OFF_STAGE 3603152    // 782*1536 u32 = 4804608
#define OFF_AB    8407760    // M_PAD x 256 bf16
#define OFF_H     34032336   // M_PAD x 256 bf16
#define OFF_W1T   59656912   // 256 x 256 bf16
#define OFF_W2T   59787984   // 80 x 256 bf16
#define OFF_P2    59828944   // M_PAD x 40 bf16
#define OFF_R2    63832784   // M_PAD x 40 f32
#define OFF_BSUM  71840464   // 256 int
#define OFF_BOFF  71841488   // 256 int
// end ~71.85 MB

typedef __attribute__((ext_vector_type(8))) short short8;
typedef __attribute__((ext_vector_type(4))) float f32x4;

__device__ __forceinline__ float bfu2f(unsigned u) {
  union { unsigned i; float f; } c; c.i = u << 16; return c.f;
}
__device__ __forceinline__ unsigned f2bfu(float f) {
  union { float f; unsigned i; } c; c.f = f;
  return (c.i + 0x7fffu + ((c.i >> 16) & 1u)) >> 16;   // RNE
}

#define GLOAD_LDS16(g, l)                                                      \
  __builtin_amdgcn_global_load_lds(                                            \
      (const __attribute__((address_space(1))) void*)(g),                      \
      (__attribute__((address_space(3))) void*)(l), 16, 0, 0)

// ---------------- CSR build: block-range-claimed bucket binning -------------
// Pass1: LDS bucket histogram + global node histogram.
// Claim: one global atomicAdd per (block,bucket) -> contiguous stage range.
// Pass2: write packed (src<<6 | dst&63) into claimed range (write-local).
__global__ __launch_bounds__(256) void k_binA(const int* __restrict__ src,
                                              const int* __restrict__ dst,
                                              int* __restrict__ cnt,
                                              int* __restrict__ bcur,
                                              unsigned* __restrict__ stage) {
  __shared__ int hist[NBUCKETS];
  int t = threadIdx.x;
  int e0 = blockIdx.x * EPB;
  int e1 = min(e0 + EPB, N_EDGES);
  for (int i = t; i < NBUCKETS; i += 256) hist[i] = 0;
  __syncthreads();
  for (int e = e0 + t; e < e1; e += 256) {
    int d = dst[e];
    atomicAdd(&cnt[d], 1);
    atomicAdd(&hist[d >> 6], 1);
  }
  __syncthreads();
  for (int b = t; b < NBUCKETS; b += 256) {
    int c = hist[b];
    hist[b] = c ? atomicAdd(&bcur[b], c) : 0;   // now holds global base
  }
  __syncthreads();
  for (int e = e0 + t; e < e1; e += 256) {
    int d = dst[e];
    int b = d >> 6;
    int pos = atomicAdd(&hist[b], 1);           // unique slot in claimed range
    stage[(size_t)b * BCAP + pos] = ((unsigned)src[e] << 6) | (unsigned)(d & 63);
  }
}

__global__ __launch_bounds__(256) void k_scanA(const int* __restrict__ cnt,
                                               int* __restrict__ bsum) {
  __shared__ int red[256];
  int t = threadIdx.x;
  int node = blockIdx.x * 256 + t;
  red[t] = (node < N_NODES) ? cnt[node] : 0;
  __syncthreads();
  for (int off = 128; off; off >>= 1) {
    if (t < off) red[t] += red[t + off];
    __syncthreads();
  }
  if (t == 0) bsum[blockIdx.x] = red[0];
}

__global__ __launch_bounds__(256) void k_scanB(const int* __restrict__ bsum,
                                               int* __restrict__ boff,
                                               int* __restrict__ row_ptr) {
  __shared__ int part[256];
  int t = threadIdx.x;
  int v = (t < SCAN_BLOCKS) ? bsum[t] : 0;
  part[t] = v;
  __syncthreads();
  for (int off = 1; off < 256; off <<= 1) {
    int u = (t >= off) ? part[t - off] : 0;
    __syncthreads();
    part[t] += u;
    __syncthreads();
  }
  if (t < SCAN_BLOCKS) boff[t] = part[t] - v;
  if (t == 255) row_ptr[N_NODES] = part[255];
}

__global__ __launch_bounds__(256) void k_scanC(const int* __restrict__ cnt,
                                               const int* __restrict__ boff,
                                               int* __restrict__ row_ptr) {
  __shared__ int part[256];
  int t = threadIdx.x;
  int node = blockIdx.x * 256 + t;
  int v = (node < N_NODES) ? cnt[node] : 0;
  part[t] = v;
  __syncthreads();
  for (int off = 1; off < 256; off <<= 1) {
    int u = (t >= off) ? part[t - off] : 0;
    __syncthreads();
    part[t] += u;
    __syncthreads();
  }
  if (node < N_NODES) row_ptr[node] = boff[blockIdx.x] + part[t] - v;
}

// per bucket: LDS scatter to node order, coalesced esrc write
__global__ __launch_bounds__(256) void k_bsort(const unsigned* __restrict__ stage,
                                               const int* __restrict__ bcur,
                                               const int* __restrict__ row_ptr,
                                               int* __restrict__ esrc) {
  __shared__ int lcur[64];
  __shared__ int lout[BCAP];
  int b = blockIdx.x;
  int t = threadIdx.x;
  int n0 = b * 64;
  int base = row_ptr[min(n0, N_NODES)];
  if (t < 64) lcur[t] = row_ptr[min(n0 + t, N_NODES)] - base;
  __syncthreads();
  int nb = bcur[b];
  const unsigned* sp = stage + (size_t)b * BCAP;
  for (int e = t; e < nb; e += 256) {
    unsigned p = sp[e];
    int lp = atomicAdd(&lcur[p & 63u], 1);
    lout[lp] = (int)(p >> 6);
  }
  __syncthreads();
  for (int i = t; i < nb; i += 256) esrc[base + i] = lout[i];
}

// ---------------- conversions ----------------
__global__ __launch_bounds__(256) void k_convx(const float* __restrict__ x,
                                               char* __restrict__ ABb) {
  int t = blockIdx.x * 256 + threadIdx.x;
  int row = t >> 4, c8 = (t & 15) << 3;
  if (row >= N_NODES) return;
  const float* xp = x + (size_t)row * IN_DIM + c8;
  unsigned short o[8];
#pragma unroll
  for (int i = 0; i < 8; ++i) o[i] = (unsigned short)f2bfu(xp[i]);
  *(short8*)(ABb + (size_t)row * 512 + 256 + c8 * 2) = *(short8*)o;
}

// blocks 0..255: Wt1 col n; blocks 256..335: Wt2 col n-256
__global__ __launch_bounds__(256) void k_convw(const float* __restrict__ W1l,
                                               const float* __restrict__ W1r,
                                               const float* __restrict__ W2l,
                                               const float* __restrict__ W2r,
                                               unsigned short* __restrict__ Wt1,
                                               unsigned short* __restrict__ Wt2) {
  int k = threadIdx.x;
  if (blockIdx.x < 256) {
    int n = blockIdx.x;
    float v = (k < 128) ? W1l[(size_t)k * HID_DIM + n]
                        : W1r[(size_t)(k - 128) * HID_DIM + n];
    Wt1[(size_t)n * 256 + k] = (unsigned short)f2bfu(v);
  } else {
    int n = blockIdx.x - 256;
    float v = (n < OUT_DIM) ? W2l[(size_t)k * OUT_DIM + n]
                            : W2r[(size_t)k * OUT_DIM + (n - OUT_DIM)];
    Wt2[(size_t)n * 256 + k] = (unsigned short)f2bfu(v);
  }
}

// ---------------- aggregation 1 (bf16 gather, mean) ----------------
__global__ __launch_bounds__(256) void k_agg1(char* __restrict__ ABb,
    const int* __restrict__ row_ptr, const int* __restrict__ esrc) {
  int tid = threadIdx.x;
  int node = blockIdx.x * 4 + (tid >> 6);
  int lane = tid & 63;
  int g = lane >> 4;        // 0..3 edge subgroup
  int q = lane & 15;        // channel slot: ch q*8..q*8+7
  int beg = row_ptr[node], end = row_ptr[node + 1];
  float s[8];
#pragma unroll
  for (int j = 0; j < 8; ++j) s[j] = 0.f;

  for (int e0 = beg; e0 < end; e0 += 4) {
    int e = e0 + g;
    if (e < end) {
      int srcn = esrc[e];
      short8 v = *(const short8*)(ABb + (size_t)srcn * 512 + 256 + q * 16);
#pragma unroll
      for (int j = 0; j < 8; ++j)
        s[j] += bfu2f((unsigned short)v[j]);
    }
  }
#pragma unroll
  for (int j = 0; j < 8; ++j) {
    s[j] += __shfl_xor(s[j], 16, 64);
    s[j] += __shfl_xor(s[j], 32, 64);
  }
  float inv = 1.0f / (float)max(end - beg, 1);
  if (lane < 16) {
    unsigned short o[8];
#pragma unroll
    for (int j = 0; j < 8; ++j) o[j] = (unsigned short)f2bfu(s[j] * inv);
    *(short8*)(ABb + (size_t)node * 512 + q * 16) = *(short8*)o;
  }
}

// ---------------- GEMM1: H = relu(AB @ W1cat + b1), bf16 MFMA ----------------
__global__ __launch_bounds__(256) void k_gemm1(
    const char* __restrict__ ABb, const short* __restrict__ Wt1,
    const float* __restrict__ b1, unsigned short* __restrict__ H) {
  __shared__ __align__(16) char As[64 * 512];
  const int tid = threadIdx.x;
  const int w = tid >> 6, lane = tid & 63;
  const int row0 = blockIdx.x * 64;

  {
    const char* gbase = ABb + (size_t)row0 * 512;
#pragma unroll
    for (int i = 0; i < 8; ++i) {
      int o = i * 4096 + w * 1024 + lane * 16;
      int row = o >> 9;
      int kslot = ((o & 511) >> 4) ^ (row & 7);
      GLOAD_LDS16(gbase + row * 512 + kslot * 16, As + i * 4096 + w * 1024);
    }
  }
  __syncthreads();

  f32x4 acc[4][4];
#pragma unroll
  for (int mi = 0; mi < 4; ++mi)
#pragma unroll
    for (int ni = 0; ni < 4; ++ni) acc[mi][ni] = (f32x4){0.f, 0.f, 0.f, 0.f};

  const short* wb = Wt1 + (size_t)(w * 64 + (lane & 15)) * 256 + (lane >> 4) * 8;

  for (int ks = 0; ks < 8; ++ks) {
    short8 af[4], bf[4];
#pragma unroll
    for (int mi = 0; mi < 4; ++mi) {
      int row = mi * 16 + (lane & 15);
      int kslot = (ks * 4 + (lane >> 4)) ^ (row & 7);
      af[mi] = *(const short8*)(As + row * 512 + kslot * 16);
    }
#pragma unroll
    for (int ni = 0; ni < 4; ++ni)
      bf[ni] = *(const short8*)(wb + ni * 16 * 256 + ks * 32);
#pragma unroll
    for (int mi = 0; mi < 4; ++mi)
#pragma unroll
      for (int ni = 0; ni < 4; ++ni)
        acc[mi][ni] = __builtin_amdgcn_mfma_f32_16x16x32_bf16(
            af[mi], bf[ni], acc[mi][ni], 0, 0, 0);
  }

#pragma unroll
  for (int ni = 0; ni < 4; ++ni) {
    int col = w * 64 + ni * 16 + (lane & 15);
    float bv = b1[col];
#pragma unroll
    for (int mi = 0; mi < 4; ++mi) {
      int rbase = row0 + mi * 16 + (lane >> 4) * 4;
#pragma unroll
      for (int r = 0; r < 4; ++r) {
        float v = fmaxf(acc[mi][ni][r] + bv, 0.f);
        H[(size_t)(rbase + r) * 256 + col] = (unsigned short)f2bfu(v);
      }
    }
  }
}

// ---------------- GEMM2: [p2|r2] = H @ W2cat (+b2 on r2), bf16 MFMA ----------
__global__ __launch_bounds__(256) void k_gemm2(
    const char* __restrict__ Hb, const short* __restrict__ Wt2,
    const float* __restrict__ b2, unsigned short* __restrict__ P2,
    float* __restrict__ R2) {
  __shared__ __align__(16) char As[64 * 512];
  const int tid = threadIdx.x;
  const int w = tid >> 6, lane = tid & 63;
  const int row0 = blockIdx.x * 64;

  {
    const char* gbase = Hb + (size_t)row0 * 512;
#pragma unroll
    for (int i = 0; i < 8; ++i) {
      int o = i * 4096 + w * 1024 + lane * 16;
      int row = o >> 9;
      int kslot = ((o & 511) >> 4) ^ (row & 7);
      GLOAD_LDS16(gbase + row * 512 + kslot * 16, As + i * 4096 + w * 1024);
    }
  }
  __syncthreads();

  f32x4 acc[5];
#pragma unroll
  for (int ni = 0; ni < 5; ++ni) acc[ni] = (f32x4){0.f, 0.f, 0.f, 0.f};

  const short* wb = Wt2 + (size_t)(lane & 15) * 256 + (lane >> 4) * 8;
  const int arow = w * 16 + (lane & 15);

  for (int ks = 0; ks < 8; ++ks) {
    int kslot = (ks * 4 + (lane >> 4)) ^ (arow & 7);
    short8 a = *(const short8*)(As + arow * 512 + kslot * 16);
#pragma unroll
    for (int ni = 0; ni < 5; ++ni) {
      short8 bf = *(const short8*)(wb + ni * 16 * 256 + ks * 32);
      acc[ni] = __builtin_amdgcn_mfma_f32_16x16x32_bf16(a, bf, acc[ni], 0, 0, 0);
    }
  }

#pragma unroll
  for (int ni = 0; ni < 5; ++ni) {
    int col = ni * 16 + (lane & 15);
#pragma unroll
    for (int r = 0; r < 4; ++r) {
      int row = row0 + w * 16 + (lane >> 4) * 4 + r;
      float v = acc[ni][r];
      if (col < OUT_DIM) {
        P2[(size_t)row * OUT_DIM + col] = (unsigned short)f2bfu(v);
      } else {
        R2[(size_t)row * OUT_DIM + (col - OUT_DIM)] = v + b2[col - OUT_DIM];
      }
    }
  }
}

// ---------------- agg2 + log_softmax ----------------
__global__ __launch_bounds__(256) void k_agg2(const unsigned short* __restrict__ P2,
    const float* __restrict__ R2, const int* __restrict__ row_ptr,
    const int* __restrict__ esrc, float* __restrict__ out) {
  int tid = threadIdx.x;
  int node = blockIdx.x * 4 + (tid >> 6);
  int lane = tid & 63;
  int g = lane >> 3;        // 0..7 edge slot
  int q = lane & 7;         // 0..4 active: channels q*8..q*8+7
  int beg = row_ptr[node], end = row_ptr[node + 1];
  float s[8];
#pragma unroll
  for (int j = 0; j < 8; ++j) s[j] = 0.f;

  for (int e0 = beg; e0 < end; e0 += 8) {
    int e = e0 + g;
    if (e < end && q < 5) {
      int srcn = esrc[e];
      short8 v = *(const short8*)((const char*)P2 + (size_t)srcn * 80 + q * 16);
#pragma unroll
      for (int j = 0; j < 8; ++j)
        s[j] += bfu2f((unsigned short)v[j]);
    }
  }
#pragma unroll
  for (int j = 0; j < 8; ++j) {
    s[j] += __shfl_xor(s[j], 8, 64);
    s[j] += __shfl_xor(s[j], 16, 64);
    s[j] += __shfl_xor(s[j], 32, 64);
  }

  float inv = 1.0f / (float)max(end - beg, 1);
  float v[8];
  float m = -1e30f;
  if (q < 5) {
    const float* rr = R2 + (size_t)node * OUT_DIM + q * 8;
    f32x4 r0 = *(const f32x4*)rr;
    f32x4 r1 = *(const f32x4*)(rr + 4);
#pragma unroll
    for (int j = 0; j < 8; ++j) {
      float rj = (j < 4) ? r0[j] : r1[j - 4];
      v[j] = s[j] * inv + rj;
      m = fmaxf(m, v[j]);
    }
  }
#pragma unroll
  for (int o = 1; o <= 4; o <<= 1) m = fmaxf(m, __shfl_xor(m, o, 64));
  float ex = 0.f;
  if (q < 5) {
#pragma unroll
    for (int j = 0; j < 8; ++j) ex += __expf(v[j] - m);
  }
#pragma unroll
  for (int o = 1; o <= 4; o <<= 1) ex += __shfl_xor(ex, o, 64);
  float ls = __logf(ex) + m;

  if (g == 0 && q < 5) {
    float* op = out + (size_t)node * OUT_DIM + q * 8;
    f32x4 o0, o1;
#pragma unroll
    for (int j = 0; j < 4; ++j) { o0[j] = v[j] - ls; o1[j] = v[j + 4] - ls; }
    *(f32x4*)op = o0;
    *(f32x4*)(op + 4) = o1;
  }
}

extern "C" void kernel_launch(void* const* d_in, const int* in_sizes, int n_in,
                              void* d_out, int out_size, void* d_ws, size_t ws_size,
                              hipStream_t stream) {
  const float* x   = (const float*)d_in[0];
  const int*   ei  = (const int*)d_in[1];
  const float* W1l = (const float*)d_in[2];
  const float* W1r = (const float*)d_in[3];
  const float* b1  = (const float*)d_in[4];
  const float* W2l = (const float*)d_in[5];
  const float* W2r = (const float*)d_in[6];
  const float* b2  = (const float*)d_in[7];
  float* out = (float*)d_out;

  const int* src = ei;
  const int* dst = ei + N_EDGES;

  char* ws = (char*)d_ws;
  int*      cnt     = (int*)(ws + OFF_CNT);
  int*      bcur    = (int*)(ws + OFF_BCUR);
  int*      row_ptr = (int*)(ws + OFF_RP);
  int*      esrc    = (int*)(ws + OFF_ESRC);
  unsigned* stage   = (unsigned*)(ws + OFF_STAGE);
  char*     ABb     = ws + OFF_AB;
  char*     Hb      = ws + OFF_H;
  unsigned short* Wt1 = (unsigned short*)(ws + OFF_W1T);
  unsigned short* Wt2 = (unsigned short*)(ws + OFF_W2T);
  unsigned short* P2  = (unsigned short*)(ws + OFF_P2);
  float* R2   = (float*)(ws + OFF_R2);
  int*   bsum = (int*)(ws + OFF_BSUM);
  int*   boff = (int*)(ws + OFF_BOFF);

  (void)hipMemsetAsync(ws, 0, ZERO_BYTES, stream);   // cnt + bcur
  (void)hipMemsetAsync(ABb + (size_t)N_NODES * 512, 0, (M_PAD - N_NODES) * 512,
                       stream);

  k_convx<<<(N_NODES * 16 + 255) / 256, 256, 0, stream>>>(x, ABb);
  k_convw<<<336, 256, 0, stream>>>(W1l, W1r, W2l, W2r, Wt1, Wt2);

  k_binA<<<BINA_BLOCKS, 256, 0, stream>>>(src, dst, cnt, bcur, stage);
  k_scanA<<<SCAN_BLOCKS, 256, 0, stream>>>(cnt, bsum);
  k_scanB<<<1, 256, 0, stream>>>(bsum, boff, row_ptr);
  k_scanC<<<SCAN_BLOCKS, 256, 0, stream>>>(cnt, boff, row_ptr);
  k_bsort<<<NBUCKETS, 256, 0, stream>>>(stage, bcur, row_ptr, esrc);

  k_agg1<<<N_NODES / 4, 256, 0, stream>>>(ABb, row_ptr, esrc);
  k_gemm1<<<M_PAD / 64, 256, 0, stream>>>(ABb, (const short*)Wt1, b1,
                                          (unsigned short*)Hb);
  k_gemm2<<<M_PAD / 64, 256, 0, stream>>>(Hb, (const short*)Wt2, b2, P2, R2);
  k_agg2<<<N_NODES / 4, 256, 0, stream>>>(P2, R2, row_ptr, esrc, out);
}

// Round 11
// 229.030 us; speedup vs baseline: 1.9645x; 1.2454x over previous
//
#include <hip/hip_runtime.h>
#include <hip/hip_bf16.h>

#define N_NODES 50000
#define N_EDGES 800000
#define IN_DIM 128
#define HID_DIM 256
#define OUT_DIM 40
#define M_PAD 50048      // 782 * 64
#define NBUCKETS 782     // 64 nodes per bucket
#define EPB 8192         // edges per binning block
#define BINA_BLOCKS 98   // ceil(800000/8192)
#define BLK_PAD 128      // per-bucket block-count row, padded

// ---- workspace layout (bytes), 16-B aligned ----
#define OFF_RP     0         // 50001 int
#define OFF_ESRC   200064    // 800000 int
#define OFF_STAGE  3400064   // 800000 u32 (final bucket-sorted order)
#define OFF_HISTG  6600064   // 782*128 int
#define OFF_PFXG   7000448   // 782*128 int
#define OFF_BTOT   7400832   // 782 int
#define OFF_BBASE  7403968   // 783 int
#define OFF_AB     7407104   // M_PAD x 256 bf16
#define OFF_H      33031680  // M_PAD x 256 bf16
#define OFF_W1T    58656256  // 256 x 256 bf16
#define OFF_W2T    58787328  // 80 x 256 bf16
#define OFF_P2     58828288  // M_PAD x 40 bf16
#define OFF_R2     62832128  // M_PAD x 40 f32
// end 70839808 (~70.8 MB)

typedef __attribute__((ext_vector_type(8))) short short8;
typedef __attribute__((ext_vector_type(4))) float f32x4;

__device__ __forceinline__ float bfu2f(unsigned u) {
  union { unsigned i; float f; } c; c.i = u << 16; return c.f;
}
__device__ __forceinline__ unsigned f2bfu(float f) {
  union { float f; unsigned i; } c; c.f = f;
  return (c.i + 0x7fffu + ((c.i >> 16) & 1u)) >> 16;   // RNE
}

#define GLOAD_LDS16(g, l)                                                      \
  __builtin_amdgcn_global_load_lds(                                            \
      (const __attribute__((address_space(1))) void*)(g),                      \
      (__attribute__((address_space(3))) void*)(l), 16, 0, 0)

// ---------------- CSR build (atomic-free deterministic bucket sort) ---------
// 1) per-block LDS bucket histogram
__global__ __launch_bounds__(1024) void k_hist(const int* __restrict__ dst,
                                               int* __restrict__ hist_g) {
  __shared__ int hist[NBUCKETS];
  int t = threadIdx.x, blk = blockIdx.x;
  for (int b = t; b < NBUCKETS; b += 1024) hist[b] = 0;
  __syncthreads();
  int e0 = blk * EPB, e1 = min(e0 + EPB, N_EDGES);
  for (int e = e0 + t; e < e1; e += 1024) atomicAdd(&hist[dst[e] >> 6], 1);
  __syncthreads();
  for (int b = t; b < NBUCKETS; b += 1024) hist_g[b * BLK_PAD + blk] = hist[b];
}

// 2) per-bucket scan over the 98 block counts (one wave per bucket)
__global__ __launch_bounds__(256) void k_hscanA(const int* __restrict__ hist_g,
                                                int* __restrict__ pfx_g,
                                                int* __restrict__ btot) {
  int wave = blockIdx.x * 4 + (threadIdx.x >> 6);
  int lane = threadIdx.x & 63;
  if (wave >= NBUCKETS) return;
  const int* h = hist_g + wave * BLK_PAD;
  int v0 = (lane < BINA_BLOCKS) ? h[lane] : 0;
  int v1 = (lane + 64 < BINA_BLOCKS) ? h[lane + 64] : 0;
  int s0 = v0;
#pragma unroll
  for (int d = 1; d < 64; d <<= 1) {
    int u = __shfl_up(s0, d, 64);
    if (lane >= d) s0 += u;
  }
  int tot0 = __shfl(s0, 63, 64);
  int s1 = v1;
#pragma unroll
  for (int d = 1; d < 64; d <<= 1) {
    int u = __shfl_up(s1, d, 64);
    if (lane >= d) s1 += u;
  }
  s1 += tot0;
  pfx_g[wave * BLK_PAD + lane] = s0 - v0;
  if (lane + 64 < BLK_PAD) pfx_g[wave * BLK_PAD + lane + 64] = s1 - v1;
  if (lane == 63) btot[wave] = s1;
}

// 3) scan 782 bucket totals -> bbase
__global__ __launch_bounds__(1024) void k_hscanB(const int* __restrict__ btot,
                                                 int* __restrict__ bbase,
                                                 int* __restrict__ row_ptr) {
  __shared__ int part[1024];
  int t = threadIdx.x;
  int v = (t < NBUCKETS) ? btot[t] : 0;
  part[t] = v;
  __syncthreads();
  for (int off = 1; off < 1024; off <<= 1) {
    int u = (t >= off) ? part[t - off] : 0;
    __syncthreads();
    part[t] += u;
    __syncthreads();
  }
  if (t < NBUCKETS) bbase[t] = part[t] - v;
  if (t == NBUCKETS - 1) {
    bbase[NBUCKETS] = part[t];
    row_ptr[N_NODES] = part[t];
  }
}

// 4) write edges into exact bucket-sorted slots (LDS cursors, no global atomics)
__global__ __launch_bounds__(1024) void k_fill2(const int* __restrict__ src,
                                                const int* __restrict__ dst,
                                                const int* __restrict__ bbase,
                                                const int* __restrict__ pfx_g,
                                                unsigned* __restrict__ stage) {
  __shared__ int cur[NBUCKETS];
  int t = threadIdx.x, blk = blockIdx.x;
  for (int b = t; b < NBUCKETS; b += 1024)
    cur[b] = bbase[b] + pfx_g[b * BLK_PAD + blk];
  __syncthreads();
  int e0 = blk * EPB, e1 = min(e0 + EPB, N_EDGES);
  for (int e = e0 + t; e < e1; e += 1024) {
    int d = dst[e];
    int pos = atomicAdd(&cur[d >> 6], 1);
    stage[pos] = ((unsigned)src[e] << 6) | (unsigned)(d & 63);
  }
}

// 5) per bucket: node counts -> row_ptr, LDS scatter, coalesced esrc
__global__ __launch_bounds__(256) void k_bsort(const unsigned* __restrict__ stage,
                                               const int* __restrict__ bbase,
                                               int* __restrict__ row_ptr,
                                               int* __restrict__ esrc) {
  __shared__ int lcnt[64];
  __shared__ int lout[1536];
  int b = blockIdx.x, t = threadIdx.x;
  int base = bbase[b];
  int nb = bbase[b + 1] - base;
  if (t < 64) lcnt[t] = 0;
  __syncthreads();
  const unsigned* sp = stage + base;
  for (int e = t; e < nb; e += 256) atomicAdd(&lcnt[sp[e] & 63u], 1);
  __syncthreads();
  if (t < 64) {   // wave 0: exclusive scan of 64 node counts
    int v = lcnt[t];
    int s = v;
#pragma unroll
    for (int d = 1; d < 64; d <<= 1) {
      int u = __shfl_up(s, d, 64);
      if (t >= d) s += u;
    }
    int node = b * 64 + t;
    if (node < N_NODES) row_ptr[node] = base + s - v;
    lcnt[t] = s - v;   // reuse as cursor
  }
  __syncthreads();
  for (int e = t; e < nb; e += 256) {
    unsigned p = sp[e];
    int lp = atomicAdd(&lcnt[p & 63u], 1);
    lout[lp] = (int)(p >> 6);
  }
  __syncthreads();
  for (int i = t; i < nb; i += 256) esrc[base + i] = lout[i];
}

// ---------------- conversions ----------------
__global__ __launch_bounds__(256) void k_convx(const float* __restrict__ x,
                                               char* __restrict__ ABb) {
  int t = blockIdx.x * 256 + threadIdx.x;
  int row = t >> 4, c8 = (t & 15) << 3;
  if (row >= N_NODES) return;
  const float* xp = x + (size_t)row * IN_DIM + c8;
  unsigned short o[8];
#pragma unroll
  for (int i = 0; i < 8; ++i) o[i] = (unsigned short)f2bfu(xp[i]);
  *(short8*)(ABb + (size_t)row * 512 + 256 + c8 * 2) = *(short8*)o;
}

__global__ __launch_bounds__(256) void k_convw(const float* __restrict__ W1l,
                                               const float* __restrict__ W1r,
                                               const float* __restrict__ W2l,
                                               const float* __restrict__ W2r,
                                               unsigned short* __restrict__ Wt1,
                                               unsigned short* __restrict__ Wt2) {
  int k = threadIdx.x;
  if (blockIdx.x < 256) {
    int n = blockIdx.x;
    float v = (k < 128) ? W1l[(size_t)k * HID_DIM + n]
                        : W1r[(size_t)(k - 128) * HID_DIM + n];
    Wt1[(size_t)n * 256 + k] = (unsigned short)f2bfu(v);
  } else {
    int n = blockIdx.x - 256;
    float v = (n < OUT_DIM) ? W2l[(size_t)k * OUT_DIM + n]
                            : W2r[(size_t)k * OUT_DIM + (n - OUT_DIM)];
    Wt2[(size_t)n * 256 + k] = (unsigned short)f2bfu(v);
  }
}

// ---------------- aggregation 1 (bf16 gather, mean) ----------------
__global__ __launch_bounds__(256) void k_agg1(char* __restrict__ ABb,
    const int* __restrict__ row_ptr, const int* __restrict__ esrc) {
  int tid = threadIdx.x;
  int node = blockIdx.x * 4 + (tid >> 6);
  int lane = tid & 63;
  int g = lane >> 4;
  int q = lane & 15;
  int beg = row_ptr[node], end = row_ptr[node + 1];
  float s[8];
#pragma unroll
  for (int j = 0; j < 8; ++j) s[j] = 0.f;

  for (int e0 = beg; e0 < end; e0 += 4) {
    int e = e0 + g;
    if (e < end) {
      int srcn = esrc[e];
      short8 v = *(const short8*)(ABb + (size_t)srcn * 512 + 256 + q * 16);
#pragma unroll
      for (int j = 0; j < 8; ++j)
        s[j] += bfu2f((unsigned short)v[j]);
    }
  }
#pragma unroll
  for (int j = 0; j < 8; ++j) {
    s[j] += __shfl_xor(s[j], 16, 64);
    s[j] += __shfl_xor(s[j], 32, 64);
  }
  float inv = 1.0f / (float)max(end - beg, 1);
  if (lane < 16) {
    unsigned short o[8];
#pragma unroll
    for (int j = 0; j < 8; ++j) o[j] = (unsigned short)f2bfu(s[j] * inv);
    *(short8*)(ABb + (size_t)node * 512 + q * 16) = *(short8*)o;
  }
}

// ---------------- GEMM1: H = relu(AB @ W1cat + b1), bf16 MFMA ----------------
__global__ __launch_bounds__(256) void k_gemm1(
    const char* __restrict__ ABb, const short* __restrict__ Wt1,
    const float* __restrict__ b1, unsigned short* __restrict__ H) {
  __shared__ __align__(16) char As[64 * 512];
  const int tid = threadIdx.x;
  const int w = tid >> 6, lane = tid & 63;
  const int row0 = blockIdx.x * 64;

  {
    const char* gbase = ABb + (size_t)row0 * 512;
#pragma unroll
    for (int i = 0; i < 8; ++i) {
      int o = i * 4096 + w * 1024 + lane * 16;
      int row = o >> 9;
      int kslot = ((o & 511) >> 4) ^ (row & 7);
      GLOAD_LDS16(gbase + row * 512 + kslot * 16, As + i * 4096 + w * 1024);
    }
  }
  __syncthreads();

  f32x4 acc[4][4];
#pragma unroll
  for (int mi = 0; mi < 4; ++mi)
#pragma unroll
    for (int ni = 0; ni < 4; ++ni) acc[mi][ni] = (f32x4){0.f, 0.f, 0.f, 0.f};

  const short* wb = Wt1 + (size_t)(w * 64 + (lane & 15)) * 256 + (lane >> 4) * 8;

  for (int ks = 0; ks < 8; ++ks) {
    short8 af[4], bf[4];
#pragma unroll
    for (int mi = 0; mi < 4; ++mi) {
      int row = mi * 16 + (lane & 15);
      int kslot = (ks * 4 + (lane >> 4)) ^ (row & 7);
      af[mi] = *(const short8*)(As + row * 512 + kslot * 16);
    }
#pragma unroll
    for (int ni = 0; ni < 4; ++ni)
      bf[ni] = *(const short8*)(wb + ni * 16 * 256 + ks * 32);
#pragma unroll
    for (int mi = 0; mi < 4; ++mi)
#pragma unroll
      for (int ni = 0; ni < 4; ++ni)
        acc[mi][ni] = __builtin_amdgcn_mfma_f32_16x16x32_bf16(
            af[mi], bf[ni], acc[mi][ni], 0, 0, 0);
  }

#pragma unroll
  for (int ni = 0; ni < 4; ++ni) {
    int col = w * 64 + ni * 16 + (lane & 15);
    float bv = b1[col];
#pragma unroll
    for (int mi = 0; mi < 4; ++mi) {
      int rbase = row0 + mi * 16 + (lane >> 4) * 4;
#pragma unroll
      for (int r = 0; r < 4; ++r) {
        float v = fmaxf(acc[mi][ni][r] + bv, 0.f);
        H[(size_t)(rbase + r) * 256 + col] = (unsigned short)f2bfu(v);
      }
    }
  }
}

// ---------------- GEMM2: [p2|r2] = H @ W2cat (+b2 on r2), bf16 MFMA ----------
__global__ __launch_bounds__(256) void k_gemm2(
    const char* __restrict__ Hb, const short* __restrict__ Wt2,
    const float* __restrict__ b2, unsigned short* __restrict__ P2,
    float* __restrict__ R2) {
  __shared__ __align__(16) char As[64 * 512];
  const int tid = threadIdx.x;
  const int w = tid >> 6, lane = tid & 63;
  const int row0 = blockIdx.x * 64;

  {
    const char* gbase = Hb + (size_t)row0 * 512;
#pragma unroll
    for (int i = 0; i < 8; ++i) {
      int o = i * 4096 + w * 1024 + lane * 16;
      int row = o >> 9;
      int kslot = ((o & 511) >> 4) ^ (row & 7);
      GLOAD_LDS16(gbase + row * 512 + kslot * 16, As + i * 4096 + w * 1024);
    }
  }
  __syncthreads();

  f32x4 acc[5];
#pragma unroll
  for (int ni = 0; ni < 5; ++ni) acc[ni] = (f32x4){0.f, 0.f, 0.f, 0.f};

  const short* wb = Wt2 + (size_t)(lane & 15) * 256 + (lane >> 4) * 8;
  const int arow = w * 16 + (lane & 15);

  for (int ks = 0; ks < 8; ++ks) {
    int kslot = (ks * 4 + (lane >> 4)) ^ (arow & 7);
    short8 a = *(const short8*)(As + arow * 512 + kslot * 16);
#pragma unroll
    for (int ni = 0; ni < 5; ++ni) {
      short8 bf = *(const short8*)(wb + ni * 16 * 256 + ks * 32);
      acc[ni] = __builtin_amdgcn_mfma_f32_16x16x32_bf16(a, bf, acc[ni], 0, 0, 0);
    }
  }

#pragma unroll
  for (int ni = 0; ni < 5; ++ni) {
    int col = ni * 16 + (lane & 15);
#pragma unroll
    for (int r = 0; r < 4; ++r) {
      int row = row0 + w * 16 + (lane >> 4) * 4 + r;
      float v = acc[ni][r];
      if (col < OUT_DIM) {
        P2[(size_t)row * OUT_DIM + col] = (unsigned short)f2bfu(v);
      } else {
        R2[(size_t)row * OUT_DIM + (col - OUT_DIM)] = v + b2[col - OUT_DIM];
      }
    }
  }
}

// ---------------- agg2 + log_softmax ----------------
__global__ __launch_bounds__(256) void k_agg2(const unsigned short* __restrict__ P2,
    const float* __restrict__ R2, const int* __restrict__ row_ptr,
    const int* __restrict__ esrc, float* __restrict__ out) {
  int tid = threadIdx.x;
  int node = blockIdx.x * 4 + (tid >> 6);
  int lane = tid & 63;
  int g = lane >> 3;
  int q = lane & 7;
  int beg = row_ptr[node], end = row_ptr[node + 1];
  float s[8];
#pragma unroll
  for (int j = 0; j < 8; ++j) s[j] = 0.f;

  for (int e0 = beg; e0 < end; e0 += 8) {
    int e = e0 + g;
    if (e < end && q < 5) {
      int srcn = esrc[e];
      short8 v = *(const short8*)((const char*)P2 + (size_t)srcn * 80 + q * 16);
#pragma unroll
      for (int j = 0; j < 8; ++j)
        s[j] += bfu2f((unsigned short)v[j]);
    }
  }
#pragma unroll
  for (int j = 0; j < 8; ++j) {
    s[j] += __shfl_xor(s[j], 8, 64);
    s[j] += __shfl_xor(s[j], 16, 64);
    s[j] += __shfl_xor(s[j], 32, 64);
  }

  float inv = 1.0f / (float)max(end - beg, 1);
  float v[8];
  float m = -1e30f;
  if (q < 5) {
    const float* rr = R2 + (size_t)node * OUT_DIM + q * 8;
    f32x4 r0 = *(const f32x4*)rr;
    f32x4 r1 = *(const f32x4*)(rr + 4);
#pragma unroll
    for (int j = 0; j < 8; ++j) {
      float rj = (j < 4) ? r0[j] : r1[j - 4];
      v[j] = s[j] * inv + rj;
      m = fmaxf(m, v[j]);
    }
  }
#pragma unroll
  for (int o = 1; o <= 4; o <<= 1) m = fmaxf(m, __shfl_xor(m, o, 64));
  float ex = 0.f;
  if (q < 5) {
#pragma unroll
    for (int j = 0; j < 8; ++j) ex += __expf(v[j] - m);
  }
#pragma unroll
  for (int o = 1; o <= 4; o <<= 1) ex += __shfl_xor(ex, o, 64);
  float ls = __logf(ex) + m;

  if (g == 0 && q < 5) {
    float* op = out + (size_t)node * OUT_DIM + q * 8;
    f32x4 o0, o1;
#pragma unroll
    for (int j = 0; j < 4; ++j) { o0[j] = v[j] - ls; o1[j] = v[j + 4] - ls; }
    *(f32x4*)op = o0;
    *(f32x4*)(op + 4) = o1;
  }
}

extern "C" void kernel_launch(void* const* d_in, const int* in_sizes, int n_in,
                              void* d_out, int out_size, void* d_ws, size_t ws_size,
                              hipStream_t stream) {
  const float* x   = (const float*)d_in[0];
  const int*   ei  = (const int*)d_in[1];
  const float* W1l = (const float*)d_in[2];
  const float* W1r = (const float*)d_in[3];
  const float* b1  = (const float*)d_in[4];
  const float* W2l = (const float*)d_in[5];
  const float* W2r = (const float*)d_in[6];
  const float* b2  = (const float*)d_in[7];
  float* out = (float*)d_out;

  const int* src = ei;
  const int* dst = ei + N_EDGES;

  char* ws = (char*)d_ws;
  int*      row_ptr = (int*)(ws + OFF_RP);
  int*      esrc    = (int*)(ws + OFF_ESRC);
  unsigned* stage   = (unsigned*)(ws + OFF_STAGE);
  int*      hist_g  = (int*)(ws + OFF_HISTG);
  int*      pfx_g   = (int*)(ws + OFF_PFXG);
  int*      btot    = (int*)(ws + OFF_BTOT);
  int*      bbase   = (int*)(ws + OFF_BBASE);
  char*     ABb     = ws + OFF_AB;
  char*     Hb      = ws + OFF_H;
  unsigned short* Wt1 = (unsigned short*)(ws + OFF_W1T);
  unsigned short* Wt2 = (unsigned short*)(ws + OFF_W2T);
  unsigned short* P2  = (unsigned short*)(ws + OFF_P2);
  float* R2 = (float*)(ws + OFF_R2);

  (void)hipMemsetAsync(ABb + (size_t)N_NODES * 512, 0, (M_PAD - N_NODES) * 512,
                       stream);

  k_convx<<<(N_NODES * 16 + 255) / 256, 256, 0, stream>>>(x, ABb);
  k_convw<<<336, 256, 0, stream>>>(W1l, W1r, W2l, W2r, Wt1, Wt2);

  k_hist<<<BINA_BLOCKS, 1024, 0, stream>>>(dst, hist_g);
  k_hscanA<<<(NBUCKETS + 3) / 4, 256, 0, stream>>>(hist_g, pfx_g, btot);
  k_hscanB<<<1, 1024, 0, stream>>>(btot, bbase, row_ptr);
  k_fill2<<<BINA_BLOCKS, 1024, 0, stream>>>(src, dst, bbase, pfx_g, stage);
  k_bsort<<<NBUCKETS, 256, 0, stream>>>(stage, bbase, row_ptr, esrc);

  k_agg1<<<N_NODES / 4, 256, 0, stream>>>(ABb, row_ptr, esrc);
  k_gemm1<<<M_PAD / 64, 256, 0, stream>>>(ABb, (const short*)Wt1, b1,
                                          (unsigned short*)Hb);
  k_gemm2<<<M_PAD / 64, 256, 0, stream>>>(Hb, (const short*)Wt2, b2, P2, R2);
  k_agg2<<<N_NODES / 4, 256, 0, stream>>>(P2, R2, row_ptr, esrc, out);
}

// Round 12
// 212.009 us; speedup vs baseline: 2.1222x; 1.0803x over previous
//
#include <hip/hip_runtime.h>
#include <hip/hip_bf16.h>

#define N_NODES 50000
#define N_EDGES 800000
#define IN_DIM 128
#define HID_DIM 256
#define OUT_DIM 40
#define M_PAD 50048      // 782 * 64
#define NBUCKETS 782     // 64 nodes per bucket
#define EPB 8192         // edges per binning block
#define BINA_BLOCKS 98   // ceil(800000/8192)
#define BLK_PAD 128      // per-bucket block-count row, padded
#define CONVX_BLOCKS 3125

// ---- workspace layout (bytes), 16-B aligned ----
#define OFF_RP     0         // 50001 int
#define OFF_ESRC   200064    // 800000 int
#define OFF_STAGE  3400064   // 800000 u32
#define OFF_HISTG  6600064   // 782*128 int
#define OFF_PFXG   7000448   // 782*128 int
#define OFF_BTOT   7400832   // 782 int
#define OFF_BBASE  7403968   // 783 int
#define OFF_AB     7407104   // M_PAD x 256 bf16
#define OFF_W1T    33031680  // 256 x 256 bf16
#define OFF_W2T    33162752  // 80 x 256 bf16
#define OFF_P2     33203712  // M_PAD x 40 bf16
#define OFF_R2     37207552  // M_PAD x 40 f32
// end 45215232 (~45 MB)

typedef __attribute__((ext_vector_type(8))) short short8;
typedef __attribute__((ext_vector_type(4))) float f32x4;

__device__ __forceinline__ float bfu2f(unsigned u) {
  union { unsigned i; float f; } c; c.i = u << 16; return c.f;
}
__device__ __forceinline__ unsigned f2bfu(float f) {
  union { float f; unsigned i; } c; c.f = f;
  return (c.i + 0x7fffu + ((c.i >> 16) & 1u)) >> 16;   // RNE
}

#define GLOAD_LDS16(g, l)                                                      \
  __builtin_amdgcn_global_load_lds(                                            \
      (const __attribute__((address_space(1))) void*)(g),                      \
      (__attribute__((address_space(3))) void*)(l), 16, 0, 0)

// ---------------- CSR build (atomic-free deterministic bucket sort) ---------
__global__ __launch_bounds__(1024) void k_hist(const int* __restrict__ dst,
                                               int* __restrict__ hist_g) {
  __shared__ int hist[NBUCKETS];
  int t = threadIdx.x, blk = blockIdx.x;
  for (int b = t; b < NBUCKETS; b += 1024) hist[b] = 0;
  __syncthreads();
  int e0 = blk * EPB, e1 = min(e0 + EPB, N_EDGES);
  for (int e = e0 + t; e < e1; e += 1024) atomicAdd(&hist[dst[e] >> 6], 1);
  __syncthreads();
  for (int b = t; b < NBUCKETS; b += 1024) hist_g[b * BLK_PAD + blk] = hist[b];
}

__global__ __launch_bounds__(256) void k_hscanA(const int* __restrict__ hist_g,
                                                int* __restrict__ pfx_g,
                                                int* __restrict__ btot) {
  int wave = blockIdx.x * 4 + (threadIdx.x >> 6);
  int lane = threadIdx.x & 63;
  if (wave >= NBUCKETS) return;
  const int* h = hist_g + wave * BLK_PAD;
  int v0 = (lane < BINA_BLOCKS) ? h[lane] : 0;
  int v1 = (lane + 64 < BINA_BLOCKS) ? h[lane + 64] : 0;
  int s0 = v0;
#pragma unroll
  for (int d = 1; d < 64; d <<= 1) {
    int u = __shfl_up(s0, d, 64);
    if (lane >= d) s0 += u;
  }
  int tot0 = __shfl(s0, 63, 64);
  int s1 = v1;
#pragma unroll
  for (int d = 1; d < 64; d <<= 1) {
    int u = __shfl_up(s1, d, 64);
    if (lane >= d) s1 += u;
  }
  s1 += tot0;
  pfx_g[wave * BLK_PAD + lane] = s0 - v0;
  if (lane + 64 < BLK_PAD) pfx_g[wave * BLK_PAD + lane + 64] = s1 - v1;
  if (lane == 63) btot[wave] = s1;
}

__global__ __launch_bounds__(1024) void k_hscanB(const int* __restrict__ btot,
                                                 int* __restrict__ bbase,
                                                 int* __restrict__ row_ptr) {
  __shared__ int part[1024];
  int t = threadIdx.x;
  int v = (t < NBUCKETS) ? btot[t] : 0;
  part[t] = v;
  __syncthreads();
  for (int off = 1; off < 1024; off <<= 1) {
    int u = (t >= off) ? part[t - off] : 0;
    __syncthreads();
    part[t] += u;
    __syncthreads();
  }
  if (t < NBUCKETS) bbase[t] = part[t] - v;
  if (t == NBUCKETS - 1) {
    bbase[NBUCKETS] = part[t];
    row_ptr[N_NODES] = part[t];
  }
}

__global__ __launch_bounds__(1024) void k_fill2(const int* __restrict__ src,
                                                const int* __restrict__ dst,
                                                const int* __restrict__ bbase,
                                                const int* __restrict__ pfx_g,
                                                unsigned* __restrict__ stage) {
  __shared__ int cur[NBUCKETS];
  int t = threadIdx.x, blk = blockIdx.x;
  for (int b = t; b < NBUCKETS; b += 1024)
    cur[b] = bbase[b] + pfx_g[b * BLK_PAD + blk];
  __syncthreads();
  int e0 = blk * EPB, e1 = min(e0 + EPB, N_EDGES);
  for (int e = e0 + t; e < e1; e += 1024) {
    int d = dst[e];
    int pos = atomicAdd(&cur[d >> 6], 1);
    stage[pos] = ((unsigned)src[e] << 6) | (unsigned)(d & 63);
  }
}

__global__ __launch_bounds__(256) void k_bsort(const unsigned* __restrict__ stage,
                                               const int* __restrict__ bbase,
                                               int* __restrict__ row_ptr,
                                               int* __restrict__ esrc) {
  __shared__ int lcnt[64];
  __shared__ int lout[1536];
  int b = blockIdx.x, t = threadIdx.x;
  int base = bbase[b];
  int nb = bbase[b + 1] - base;
  if (t < 64) lcnt[t] = 0;
  __syncthreads();
  const unsigned* sp = stage + base;
  for (int e = t; e < nb; e += 256) atomicAdd(&lcnt[sp[e] & 63u], 1);
  __syncthreads();
  if (t < 64) {
    int v = lcnt[t];
    int s = v;
#pragma unroll
    for (int d = 1; d < 64; d <<= 1) {
      int u = __shfl_up(s, d, 64);
      if (t >= d) s += u;
    }
    int node = b * 64 + t;
    if (node < N_NODES) row_ptr[node] = base + s - v;
    lcnt[t] = s - v;
  }
  __syncthreads();
  for (int e = t; e < nb; e += 256) {
    unsigned p = sp[e];
    int lp = atomicAdd(&lcnt[p & 63u], 1);
    lout[lp] = (int)(p >> 6);
  }
  __syncthreads();
  for (int i = t; i < nb; i += 256) esrc[base + i] = lout[i];
}

// ---------------- conversions (merged) ----------------
__global__ __launch_bounds__(256) void k_conv(const float* __restrict__ x,
                                              char* __restrict__ ABb,
                                              const float* __restrict__ W1l,
                                              const float* __restrict__ W1r,
                                              const float* __restrict__ W2l,
                                              const float* __restrict__ W2r,
                                              unsigned short* __restrict__ Wt1,
                                              unsigned short* __restrict__ Wt2) {
  if (blockIdx.x < CONVX_BLOCKS) {
    int t = blockIdx.x * 256 + threadIdx.x;
    int row = t >> 4, c8 = (t & 15) << 3;
    const float* xp = x + (size_t)row * IN_DIM + c8;
    unsigned short o[8];
#pragma unroll
    for (int i = 0; i < 8; ++i) o[i] = (unsigned short)f2bfu(xp[i]);
    *(short8*)(ABb + (size_t)row * 512 + 256 + c8 * 2) = *(short8*)o;
  } else if (blockIdx.x < CONVX_BLOCKS + 256) {
    int n = blockIdx.x - CONVX_BLOCKS;
    int k = threadIdx.x;
    float v = (k < 128) ? W1l[(size_t)k * HID_DIM + n]
                        : W1r[(size_t)(k - 128) * HID_DIM + n];
    Wt1[(size_t)n * 256 + k] = (unsigned short)f2bfu(v);
  } else {
    int n = blockIdx.x - CONVX_BLOCKS - 256;
    int k = threadIdx.x;
    float v = (n < OUT_DIM) ? W2l[(size_t)k * OUT_DIM + n]
                            : W2r[(size_t)k * OUT_DIM + (n - OUT_DIM)];
    Wt2[(size_t)n * 256 + k] = (unsigned short)f2bfu(v);
  }
}

// ---------------- aggregation 1 (bf16 gather, mean, 2x unrolled) ------------
__global__ __launch_bounds__(256) void k_agg1(char* __restrict__ ABb,
    const int* __restrict__ row_ptr, const int* __restrict__ esrc) {
  int tid = threadIdx.x;
  int node = blockIdx.x * 4 + (tid >> 6);
  int lane = tid & 63;
  int g = lane >> 4;
  int q = lane & 15;
  int beg = row_ptr[node], end = row_ptr[node + 1];
  float s[8];
#pragma unroll
  for (int j = 0; j < 8; ++j) s[j] = 0.f;

  for (int e0 = beg; e0 < end; e0 += 8) {
    int eA = e0 + g;
    int eB = eA + 4;
    int iA = min(eA, end - 1);
    int iB = min(eB, end - 1);
    int sA = esrc[iA], sB = esrc[iB];
    float wA = (eA < end) ? 1.f : 0.f;
    float wB = (eB < end) ? 1.f : 0.f;
    short8 vA = *(const short8*)(ABb + (size_t)sA * 512 + 256 + q * 16);
    short8 vB = *(const short8*)(ABb + (size_t)sB * 512 + 256 + q * 16);
#pragma unroll
    for (int j = 0; j < 8; ++j)
      s[j] = fmaf(wA, bfu2f((unsigned short)vA[j]), s[j]);
#pragma unroll
    for (int j = 0; j < 8; ++j)
      s[j] = fmaf(wB, bfu2f((unsigned short)vB[j]), s[j]);
  }
#pragma unroll
  for (int j = 0; j < 8; ++j) {
    s[j] += __shfl_xor(s[j], 16, 64);
    s[j] += __shfl_xor(s[j], 32, 64);
  }
  float inv = 1.0f / (float)max(end - beg, 1);
  if (lane < 16) {
    unsigned short o[8];
#pragma unroll
    for (int j = 0; j < 8; ++j) o[j] = (unsigned short)f2bfu(s[j] * inv);
    *(short8*)(ABb + (size_t)node * 512 + q * 16) = *(short8*)o;
  }
}

// ---------------- fused GEMM: H=relu(AB@W1+b1) in LDS; [P2|R2]=H@W2(+b2) ----
__global__ __launch_bounds__(256) void k_gemm(
    const char* __restrict__ ABb, const short* __restrict__ Wt1,
    const short* __restrict__ Wt2, const float* __restrict__ b1,
    const float* __restrict__ b2, unsigned short* __restrict__ P2,
    float* __restrict__ R2) {
  __shared__ __align__(16) char As[64 * 512];
  const int tid = threadIdx.x;
  const int w = tid >> 6, lane = tid & 63;
  const int row0 = blockIdx.x * 64;

  {  // stage AB tile: swizzled source -> linear LDS
    const char* gbase = ABb + (size_t)row0 * 512;
#pragma unroll
    for (int i = 0; i < 8; ++i) {
      int o = i * 4096 + w * 1024 + lane * 16;
      int row = o >> 9;
      int kslot = ((o & 511) >> 4) ^ (row & 7);
      GLOAD_LDS16(gbase + row * 512 + kslot * 16, As + i * 4096 + w * 1024);
    }
  }
  __syncthreads();

  // ---- phase 1: layer-1 MFMAs ----
  f32x4 acc[4][4];
#pragma unroll
  for (int mi = 0; mi < 4; ++mi)
#pragma unroll
    for (int ni = 0; ni < 4; ++ni) acc[mi][ni] = (f32x4){0.f, 0.f, 0.f, 0.f};

  const short* wb1 = Wt1 + (size_t)(w * 64 + (lane & 15)) * 256 + (lane >> 4) * 8;

  for (int ks = 0; ks < 8; ++ks) {
    short8 af[4], bf[4];
#pragma unroll
    for (int mi = 0; mi < 4; ++mi) {
      int row = mi * 16 + (lane & 15);
      int kslot = (ks * 4 + (lane >> 4)) ^ (row & 7);
      af[mi] = *(const short8*)(As + row * 512 + kslot * 16);
    }
#pragma unroll
    for (int ni = 0; ni < 4; ++ni)
      bf[ni] = *(const short8*)(wb1 + ni * 16 * 256 + ks * 32);
#pragma unroll
    for (int mi = 0; mi < 4; ++mi)
#pragma unroll
      for (int ni = 0; ni < 4; ++ni)
        acc[mi][ni] = __builtin_amdgcn_mfma_f32_16x16x32_bf16(
            af[mi], bf[ni], acc[mi][ni], 0, 0, 0);
  }

  __syncthreads();   // all waves done READING As

  // ---- epilogue 1: H = relu(acc + b1) -> LDS bf16, write-side XOR swizzle --
#pragma unroll
  for (int ni = 0; ni < 4; ++ni) {
    int col = w * 64 + ni * 16 + (lane & 15);
    float bv = b1[col];
#pragma unroll
    for (int mi = 0; mi < 4; ++mi) {
#pragma unroll
      for (int r = 0; r < 4; ++r) {
        int row = mi * 16 + (lane >> 4) * 4 + r;
        float v = fmaxf(acc[mi][ni][r] + bv, 0.f);
        int gr = (col >> 3) ^ (row & 7);
        *(unsigned short*)(As + row * 512 + gr * 16 + (col & 7) * 2) =
            (unsigned short)f2bfu(v);
      }
    }
  }
  __syncthreads();

  // ---- phase 2: layer-2 MFMAs from LDS H ----
  f32x4 acc2[5];
#pragma unroll
  for (int ni = 0; ni < 5; ++ni) acc2[ni] = (f32x4){0.f, 0.f, 0.f, 0.f};

  const short* wb2 = Wt2 + (size_t)(lane & 15) * 256 + (lane >> 4) * 8;
  const int arow = w * 16 + (lane & 15);

  for (int ks = 0; ks < 8; ++ks) {
    int kslot = (ks * 4 + (lane >> 4)) ^ (arow & 7);
    short8 a = *(const short8*)(As + arow * 512 + kslot * 16);
#pragma unroll
    for (int ni = 0; ni < 5; ++ni) {
      short8 bf = *(const short8*)(wb2 + ni * 16 * 256 + ks * 32);
      acc2[ni] = __builtin_amdgcn_mfma_f32_16x16x32_bf16(a, bf, acc2[ni], 0, 0, 0);
    }
  }

#pragma unroll
  for (int ni = 0; ni < 5; ++ni) {
    int col = ni * 16 + (lane & 15);
#pragma unroll
    for (int r = 0; r < 4; ++r) {
      int row = row0 + w * 16 + (lane >> 4) * 4 + r;
      float v = acc2[ni][r];
      if (col < OUT_DIM) {
        P2[(size_t)row * OUT_DIM + col] = (unsigned short)f2bfu(v);
      } else {
        R2[(size_t)row * OUT_DIM + (col - OUT_DIM)] = v + b2[col - OUT_DIM];
      }
    }
  }
}

// ---------------- agg2 + log_softmax ----------------
__global__ __launch_bounds__(256) void k_agg2(const unsigned short* __restrict__ P2,
    const float* __restrict__ R2, const int* __restrict__ row_ptr,
    const int* __restrict__ esrc, float* __restrict__ out) {
  int tid = threadIdx.x;
  int node = blockIdx.x * 4 + (tid >> 6);
  int lane = tid & 63;
  int g = lane >> 3;
  int q = lane & 7;
  int beg = row_ptr[node], end = row_ptr[node + 1];
  float s[8];
#pragma unroll
  for (int j = 0; j < 8; ++j) s[j] = 0.f;

  for (int e0 = beg; e0 < end; e0 += 8) {
    int e = e0 + g;
    if (e < end && q < 5) {
      int srcn = esrc[e];
      short8 v = *(const short8*)((const char*)P2 + (size_t)srcn * 80 + q * 16);
#pragma unroll
      for (int j = 0; j < 8; ++j)
        s[j] += bfu2f((unsigned short)v[j]);
    }
  }
#pragma unroll
  for (int j = 0; j < 8; ++j) {
    s[j] += __shfl_xor(s[j], 8, 64);
    s[j] += __shfl_xor(s[j], 16, 64);
    s[j] += __shfl_xor(s[j], 32, 64);
  }

  float inv = 1.0f / (float)max(end - beg, 1);
  float v[8];
  float m = -1e30f;
  if (q < 5) {
    const float* rr = R2 + (size_t)node * OUT_DIM + q * 8;
    f32x4 r0 = *(const f32x4*)rr;
    f32x4 r1 = *(const f32x4*)(rr + 4);
#pragma unroll
    for (int j = 0; j < 8; ++j) {
      float rj = (j < 4) ? r0[j] : r1[j - 4];
      v[j] = s[j] * inv + rj;
      m = fmaxf(m, v[j]);
    }
  }
#pragma unroll
  for (int o = 1; o <= 4; o <<= 1) m = fmaxf(m, __shfl_xor(m, o, 64));
  float ex = 0.f;
  if (q < 5) {
#pragma unroll
    for (int j = 0; j < 8; ++j) ex += __expf(v[j] - m);
  }
#pragma unroll
  for (int o = 1; o <= 4; o <<= 1) ex += __shfl_xor(ex, o, 64);
  float ls = __logf(ex) + m;

  if (g == 0 && q < 5) {
    float* op = out + (size_t)node * OUT_DIM + q * 8;
    f32x4 o0, o1;
#pragma unroll
    for (int j = 0; j < 4; ++j) { o0[j] = v[j] - ls; o1[j] = v[j + 4] - ls; }
    *(f32x4*)op = o0;
    *(f32x4*)(op + 4) = o1;
  }
}

extern "C" void kernel_launch(void* const* d_in, const int* in_sizes, int n_in,
                              void* d_out, int out_size, void* d_ws, size_t ws_size,
                              hipStream_t stream) {
  const float* x   = (const float*)d_in[0];
  const int*   ei  = (const int*)d_in[1];
  const float* W1l = (const float*)d_in[2];
  const float* W1r = (const float*)d_in[3];
  const float* b1  = (const float*)d_in[4];
  const float* W2l = (const float*)d_in[5];
  const float* W2r = (const float*)d_in[6];
  const float* b2  = (const float*)d_in[7];
  float* out = (float*)d_out;

  const int* src = ei;
  const int* dst = ei + N_EDGES;

  char* ws = (char*)d_ws;
  int*      row_ptr = (int*)(ws + OFF_RP);
  int*      esrc    = (int*)(ws + OFF_ESRC);
  unsigned* stage   = (unsigned*)(ws + OFF_STAGE);
  int*      hist_g  = (int*)(ws + OFF_HISTG);
  int*      pfx_g   = (int*)(ws + OFF_PFXG);
  int*      btot    = (int*)(ws + OFF_BTOT);
  int*      bbase   = (int*)(ws + OFF_BBASE);
  char*     ABb     = ws + OFF_AB;
  unsigned short* Wt1 = (unsigned short*)(ws + OFF_W1T);
  unsigned short* Wt2 = (unsigned short*)(ws + OFF_W2T);
  unsigned short* P2  = (unsigned short*)(ws + OFF_P2);
  float* R2 = (float*)(ws + OFF_R2);

  (void)hipMemsetAsync(ABb + (size_t)N_NODES * 512, 0, (M_PAD - N_NODES) * 512,
                       stream);

  k_conv<<<CONVX_BLOCKS + 336, 256, 0, stream>>>(x, ABb, W1l, W1r, W2l, W2r,
                                                 Wt1, Wt2);

  k_hist<<<BINA_BLOCKS, 1024, 0, stream>>>(dst, hist_g);
  k_hscanA<<<(NBUCKETS + 3) / 4, 256, 0, stream>>>(hist_g, pfx_g, btot);
  k_hscanB<<<1, 1024, 0, stream>>>(btot, bbase, row_ptr);
  k_fill2<<<BINA_BLOCKS, 1024, 0, stream>>>(src, dst, bbase, pfx_g, stage);
  k_bsort<<<NBUCKETS, 256, 0, stream>>>(stage, bbase, row_ptr, esrc);

  k_agg1<<<N_NODES / 4, 256, 0, stream>>>(ABb, row_ptr, esrc);
  k_gemm<<<M_PAD / 64, 256, 0, stream>>>(ABb, (const short*)Wt1,
                                         (const short*)Wt2, b1, b2, P2, R2);
  k_agg2<<<N_NODES / 4, 256, 0, stream>>>(P2, R2, row_ptr, esrc, out);
}

// Round 13
// 209.627 us; speedup vs baseline: 2.1463x; 1.0114x over previous
//
#include <hip/hip_runtime.h>
#include <hip/hip_bf16.h>

#define N_NODES 50000
#define N_EDGES 800000
#define IN_DIM 128
#define HID_DIM 256
#define OUT_DIM 40
#define M_PAD 50048      // 782 * 64
#define NBUCKETS 782     // 64 nodes per bucket
#define EPB 8192         // edges per binning block
#define BINA_BLOCKS 98   // ceil(800000/8192)
#define BLK_PAD 128      // per-bucket block-count row, padded
#define CONVX_BLOCKS 3125

// ---- workspace layout (bytes), 16-B aligned ----
#define OFF_RP     0         // 50001 int
#define OFF_ESRC   200064    // 800000 int
#define OFF_STAGE  3400064   // 800000 u32
#define OFF_HISTG  6600064   // 782*128 int
#define OFF_PFXG   7000448   // 782*128 int
#define OFF_BTOT   7400832   // 782 int
#define OFF_BBASE  7403968   // 783 int
#define OFF_AB     7407104   // M_PAD x 256 bf16
#define OFF_W1T    33031680  // 256 x 256 bf16
#define OFF_W2T    33162752  // 80 x 256 bf16
#define OFF_P2     33203712  // M_PAD x 40 bf16
#define OFF_R2     37207552  // M_PAD x 40 f32
// end 45215232 (~45 MB)

typedef __attribute__((ext_vector_type(8))) short short8;
typedef __attribute__((ext_vector_type(4))) float f32x4;

__device__ __forceinline__ float bfu2f(unsigned u) {
  union { unsigned i; float f; } c; c.i = u << 16; return c.f;
}
__device__ __forceinline__ unsigned f2bfu(float f) {
  union { float f; unsigned i; } c; c.f = f;
  return (c.i + 0x7fffu + ((c.i >> 16) & 1u)) >> 16;   // RNE
}

#define GLOAD_LDS16(g, l)                                                      \
  __builtin_amdgcn_global_load_lds(                                            \
      (const __attribute__((address_space(1))) void*)(g),                      \
      (__attribute__((address_space(3))) void*)(l), 16, 0, 0)

// ---------------- CSR build (atomic-free deterministic bucket sort) ---------
__global__ __launch_bounds__(1024) void k_hist(const int* __restrict__ dst,
                                               int* __restrict__ hist_g) {
  __shared__ int hist[NBUCKETS];
  int t = threadIdx.x, blk = blockIdx.x;
  for (int b = t; b < NBUCKETS; b += 1024) hist[b] = 0;
  __syncthreads();
  int e0 = blk * EPB, e1 = min(e0 + EPB, N_EDGES);
  for (int e = e0 + t; e < e1; e += 1024) atomicAdd(&hist[dst[e] >> 6], 1);
  __syncthreads();
  for (int b = t; b < NBUCKETS; b += 1024) hist_g[b * BLK_PAD + blk] = hist[b];
}

__global__ __launch_bounds__(256) void k_hscanA(const int* __restrict__ hist_g,
                                                int* __restrict__ pfx_g,
                                                int* __restrict__ btot) {
  int wave = blockIdx.x * 4 + (threadIdx.x >> 6);
  int lane = threadIdx.x & 63;
  if (wave >= NBUCKETS) return;
  const int* h = hist_g + wave * BLK_PAD;
  int v0 = (lane < BINA_BLOCKS) ? h[lane] : 0;
  int v1 = (lane + 64 < BINA_BLOCKS) ? h[lane + 64] : 0;
  int s0 = v0;
#pragma unroll
  for (int d = 1; d < 64; d <<= 1) {
    int u = __shfl_up(s0, d, 64);
    if (lane >= d) s0 += u;
  }
  int tot0 = __shfl(s0, 63, 64);
  int s1 = v1;
#pragma unroll
  for (int d = 1; d < 64; d <<= 1) {
    int u = __shfl_up(s1, d, 64);
    if (lane >= d) s1 += u;
  }
  s1 += tot0;
  pfx_g[wave * BLK_PAD + lane] = s0 - v0;
  if (lane + 64 < BLK_PAD) pfx_g[wave * BLK_PAD + lane + 64] = s1 - v1;
  if (lane == 63) btot[wave] = s1;
}

__global__ __launch_bounds__(1024) void k_hscanB(const int* __restrict__ btot,
                                                 int* __restrict__ bbase,
                                                 int* __restrict__ row_ptr) {
  __shared__ int part[1024];
  int t = threadIdx.x;
  int v = (t < NBUCKETS) ? btot[t] : 0;
  part[t] = v;
  __syncthreads();
  for (int off = 1; off < 1024; off <<= 1) {
    int u = (t >= off) ? part[t - off] : 0;
    __syncthreads();
    part[t] += u;
    __syncthreads();
  }
  if (t < NBUCKETS) bbase[t] = part[t] - v;
  if (t == NBUCKETS - 1) {
    bbase[NBUCKETS] = part[t];
    row_ptr[N_NODES] = part[t];
  }
}

__global__ __launch_bounds__(1024) void k_fill2(const int* __restrict__ src,
                                                const int* __restrict__ dst,
                                                const int* __restrict__ bbase,
                                                const int* __restrict__ pfx_g,
                                                unsigned* __restrict__ stage) {
  __shared__ int cur[NBUCKETS];
  int t = threadIdx.x, blk = blockIdx.x;
  for (int b = t; b < NBUCKETS; b += 1024)
    cur[b] = bbase[b] + pfx_g[b * BLK_PAD + blk];
  __syncthreads();
  int e0 = blk * EPB, e1 = min(e0 + EPB, N_EDGES);
  for (int e = e0 + t; e < e1; e += 1024) {
    int d = dst[e];
    int pos = atomicAdd(&cur[d >> 6], 1);
    stage[pos] = ((unsigned)src[e] << 6) | (unsigned)(d & 63);
  }
}

__global__ __launch_bounds__(256) void k_bsort(const unsigned* __restrict__ stage,
                                               const int* __restrict__ bbase,
                                               int* __restrict__ row_ptr,
                                               int* __restrict__ esrc) {
  __shared__ int lcnt[64];
  __shared__ int lout[1536];
  int b = blockIdx.x, t = threadIdx.x;
  int base = bbase[b];
  int nb = bbase[b + 1] - base;
  if (t < 64) lcnt[t] = 0;
  __syncthreads();
  const unsigned* sp = stage + base;
  for (int e = t; e < nb; e += 256) atomicAdd(&lcnt[sp[e] & 63u], 1);
  __syncthreads();
  if (t < 64) {
    int v = lcnt[t];
    int s = v;
#pragma unroll
    for (int d = 1; d < 64; d <<= 1) {
      int u = __shfl_up(s, d, 64);
      if (t >= d) s += u;
    }
    int node = b * 64 + t;
    if (node < N_NODES) row_ptr[node] = base + s - v;
    lcnt[t] = s - v;
  }
  __syncthreads();
  for (int e = t; e < nb; e += 256) {
    unsigned p = sp[e];
    int lp = atomicAdd(&lcnt[p & 63u], 1);
    lout[lp] = (int)(p >> 6);
  }
  __syncthreads();
  for (int i = t; i < nb; i += 256) esrc[base + i] = lout[i];
}

// ---------------- conversions + pad-zero (merged) ----------------
__global__ __launch_bounds__(256) void k_conv(const float* __restrict__ x,
                                              char* __restrict__ ABb,
                                              const float* __restrict__ W1l,
                                              const float* __restrict__ W1r,
                                              const float* __restrict__ W2l,
                                              const float* __restrict__ W2r,
                                              unsigned short* __restrict__ Wt1,
                                              unsigned short* __restrict__ Wt2) {
  if (blockIdx.x < CONVX_BLOCKS) {
    int t = blockIdx.x * 256 + threadIdx.x;
    int row = t >> 4, c8 = (t & 15) << 3;
    const float* xp = x + (size_t)row * IN_DIM + c8;
    unsigned short o[8];
#pragma unroll
    for (int i = 0; i < 8; ++i) o[i] = (unsigned short)f2bfu(xp[i]);
    *(short8*)(ABb + (size_t)row * 512 + 256 + c8 * 2) = *(short8*)o;
  } else if (blockIdx.x < CONVX_BLOCKS + 256) {
    int n = blockIdx.x - CONVX_BLOCKS;
    int k = threadIdx.x;
    float v = (k < 128) ? W1l[(size_t)k * HID_DIM + n]
                        : W1r[(size_t)(k - 128) * HID_DIM + n];
    Wt1[(size_t)n * 256 + k] = (unsigned short)f2bfu(v);
  } else if (blockIdx.x < CONVX_BLOCKS + 336) {
    int n = blockIdx.x - CONVX_BLOCKS - 256;
    int k = threadIdx.x;
    float v = (n < OUT_DIM) ? W2l[(size_t)k * OUT_DIM + n]
                            : W2r[(size_t)k * OUT_DIM + (n - OUT_DIM)];
    Wt2[(size_t)n * 256 + k] = (unsigned short)f2bfu(v);
  } else {
    // zero the AB pad rows (24576 bytes)
    char* pad = ABb + (size_t)N_NODES * 512;
    f32x4 z = (f32x4){0.f, 0.f, 0.f, 0.f};
#pragma unroll
    for (int i = 0; i < 6; ++i)
      *(f32x4*)(pad + (threadIdx.x * 6 + i) * 16) = z;
  }
}

// ---------------- aggregation 1 (bf16 gather, mean, 2x unrolled) ------------
__global__ __launch_bounds__(256) void k_agg1(char* __restrict__ ABb,
    const int* __restrict__ row_ptr, const int* __restrict__ esrc) {
  int tid = threadIdx.x;
  int node = blockIdx.x * 4 + (tid >> 6);
  int lane = tid & 63;
  int g = lane >> 4;
  int q = lane & 15;
  int beg = row_ptr[node], end = row_ptr[node + 1];
  float s[8];
#pragma unroll
  for (int j = 0; j < 8; ++j) s[j] = 0.f;

  for (int e0 = beg; e0 < end; e0 += 8) {
    int eA = e0 + g;
    int eB = eA + 4;
    int iA = min(eA, end - 1);
    int iB = min(eB, end - 1);
    int sA = esrc[iA], sB = esrc[iB];
    float wA = (eA < end) ? 1.f : 0.f;
    float wB = (eB < end) ? 1.f : 0.f;
    short8 vA = *(const short8*)(ABb + (size_t)sA * 512 + 256 + q * 16);
    short8 vB = *(const short8*)(ABb + (size_t)sB * 512 + 256 + q * 16);
#pragma unroll
    for (int j = 0; j < 8; ++j)
      s[j] = fmaf(wA, bfu2f((unsigned short)vA[j]), s[j]);
#pragma unroll
    for (int j = 0; j < 8; ++j)
      s[j] = fmaf(wB, bfu2f((unsigned short)vB[j]), s[j]);
  }
#pragma unroll
  for (int j = 0; j < 8; ++j) {
    s[j] += __shfl_xor(s[j], 16, 64);
    s[j] += __shfl_xor(s[j], 32, 64);
  }
  float inv = 1.0f / (float)max(end - beg, 1);
  if (lane < 16) {
    unsigned short o[8];
#pragma unroll
    for (int j = 0; j < 8; ++j) o[j] = (unsigned short)f2bfu(s[j] * inv);
    *(short8*)(ABb + (size_t)node * 512 + q * 16) = *(short8*)o;
  }
}

// ---------------- fused GEMM (8 waves): H in LDS; coalesced epilogue --------
__global__ __launch_bounds__(512) void k_gemm(
    const char* __restrict__ ABb, const short* __restrict__ Wt1,
    const short* __restrict__ Wt2, const float* __restrict__ b1,
    const float* __restrict__ b2, unsigned short* __restrict__ P2,
    float* __restrict__ R2) {
  __shared__ __align__(16) char As[64 * 512];
  const int tid = threadIdx.x;
  const int w = tid >> 6, lane = tid & 63;
  const int row0 = blockIdx.x * 64;

  {  // stage AB tile: swizzled source -> linear LDS (4 rounds x 8KB)
    const char* gbase = ABb + (size_t)row0 * 512;
#pragma unroll
    for (int i = 0; i < 4; ++i) {
      int o = i * 8192 + w * 1024 + lane * 16;
      int row = o >> 9;
      int kslot = ((o & 511) >> 4) ^ (row & 7);
      GLOAD_LDS16(gbase + row * 512 + kslot * 16, As + i * 8192 + w * 1024);
    }
  }
  __syncthreads();

  // ---- phase 1: layer-1 MFMAs; wave w -> cols w*32..+31 ----
  f32x4 acc[4][2];
#pragma unroll
  for (int mi = 0; mi < 4; ++mi)
#pragma unroll
    for (int ni = 0; ni < 2; ++ni) acc[mi][ni] = (f32x4){0.f, 0.f, 0.f, 0.f};

  const short* wb1 = Wt1 + (size_t)(w * 32 + (lane & 15)) * 256 + (lane >> 4) * 8;

  for (int ks = 0; ks < 8; ++ks) {
    short8 af[4], bf[2];
#pragma unroll
    for (int mi = 0; mi < 4; ++mi) {
      int row = mi * 16 + (lane & 15);
      int kslot = (ks * 4 + (lane >> 4)) ^ (row & 7);
      af[mi] = *(const short8*)(As + row * 512 + kslot * 16);
    }
#pragma unroll
    for (int ni = 0; ni < 2; ++ni)
      bf[ni] = *(const short8*)(wb1 + ni * 16 * 256 + ks * 32);
#pragma unroll
    for (int mi = 0; mi < 4; ++mi)
#pragma unroll
      for (int ni = 0; ni < 2; ++ni)
        acc[mi][ni] = __builtin_amdgcn_mfma_f32_16x16x32_bf16(
            af[mi], bf[ni], acc[mi][ni], 0, 0, 0);
  }

  __syncthreads();   // all waves done READING As

  // ---- epilogue 1: H = relu(acc + b1) -> LDS bf16 (write-side swizzle) ----
#pragma unroll
  for (int ni = 0; ni < 2; ++ni) {
    int col = w * 32 + ni * 16 + (lane & 15);
    float bv = b1[col];
#pragma unroll
    for (int mi = 0; mi < 4; ++mi) {
#pragma unroll
      for (int r = 0; r < 4; ++r) {
        int row = mi * 16 + (lane >> 4) * 4 + r;
        float v = fmaxf(acc[mi][ni][r] + bv, 0.f);
        int gr = (col >> 3) ^ (row & 7);
        *(unsigned short*)(As + row * 512 + gr * 16 + (col & 7) * 2) =
            (unsigned short)f2bfu(v);
      }
    }
  }
  __syncthreads();

  // ---- phase 2: wave w -> rowtile rt=w>>1; cols: even w ni 0..2, odd 3..4 --
  const int rt = w >> 1;
  const int ni0 = (w & 1) ? 3 : 0;
  const int nin = (w & 1) ? 2 : 3;
  f32x4 acc2[3];
#pragma unroll
  for (int i = 0; i < 3; ++i) acc2[i] = (f32x4){0.f, 0.f, 0.f, 0.f};

  const short* wb2 = Wt2 + (size_t)(lane & 15) * 256 + (lane >> 4) * 8;
  const int arow = rt * 16 + (lane & 15);

  for (int ks = 0; ks < 8; ++ks) {
    int kslot = (ks * 4 + (lane >> 4)) ^ (arow & 7);
    short8 a = *(const short8*)(As + arow * 512 + kslot * 16);
    for (int i = 0; i < 3; ++i) {
      if (i < nin) {
        short8 bf = *(const short8*)(wb2 + (ni0 + i) * 16 * 256 + ks * 32);
        acc2[i] = __builtin_amdgcn_mfma_f32_16x16x32_bf16(a, bf, acc2[i], 0, 0, 0);
      }
    }
  }

  __syncthreads();   // done reading As (H)

  // ---- epilogue 2: acc2 -> LDS staging; coalesced global writes ----
  // LDS: P2s [64][40] u16 at 0 (5120B); R2s [64][40] f32 at 5120 (10240B)
  for (int i = 0; i < 3; ++i) {
    if (i < nin) {
      int col = (ni0 + i) * 16 + (lane & 15);
#pragma unroll
      for (int r = 0; r < 4; ++r) {
        int row = rt * 16 + (lane >> 4) * 4 + r;
        float v = acc2[i][r];
        if (col < OUT_DIM) {
          *(unsigned short*)(As + row * 80 + col * 2) = (unsigned short)f2bfu(v);
        } else {
          *(float*)(As + 5120 + row * 160 + (col - OUT_DIM) * 4) =
              v + b2[col - OUT_DIM];
        }
      }
    }
  }
  __syncthreads();

  {  // P2: 5120B contiguous; R2: 10240B contiguous
    char* p2g = (char*)P2 + (size_t)row0 * 80;
    if (tid < 320) *(f32x4*)(p2g + tid * 16) = *(const f32x4*)(As + tid * 16);
    char* r2g = (char*)R2 + (size_t)row0 * 160;
    for (int i = tid; i < 640; i += 512)
      *(f32x4*)(r2g + i * 16) = *(const f32x4*)(As + 5120 + i * 16);
  }
}

// ---------------- agg2 + log_softmax ----------------
__global__ __launch_bounds__(256) void k_agg2(const unsigned short* __restrict__ P2,
    const float* __restrict__ R2, const int* __restrict__ row_ptr,
    const int* __restrict__ esrc, float* __restrict__ out) {
  int tid = threadIdx.x;
  int node = blockIdx.x * 4 + (tid >> 6);
  int lane = tid & 63;
  int g = lane >> 3;
  int q = lane & 7;
  int beg = row_ptr[node], end = row_ptr[node + 1];
  float s[8];
#pragma unroll
  for (int j = 0; j < 8; ++j) s[j] = 0.f;

  for (int e0 = beg; e0 < end; e0 += 8) {
    int e = e0 + g;
    if (e < end && q < 5) {
      int srcn = esrc[e];
      short8 v = *(const short8*)((const char*)P2 + (size_t)srcn * 80 + q * 16);
#pragma unroll
      for (int j = 0; j < 8; ++j)
        s[j] += bfu2f((unsigned short)v[j]);
    }
  }
#pragma unroll
  for (int j = 0; j < 8; ++j) {
    s[j] += __shfl_xor(s[j], 8, 64);
    s[j] += __shfl_xor(s[j], 16, 64);
    s[j] += __shfl_xor(s[j], 32, 64);
  }

  float inv = 1.0f / (float)max(end - beg, 1);
  float v[8];
  float m = -1e30f;
  if (q < 5) {
    const float* rr = R2 + (size_t)node * OUT_DIM + q * 8;
    f32x4 r0 = *(const f32x4*)rr;
    f32x4 r1 = *(const f32x4*)(rr + 4);
#pragma unroll
    for (int j = 0; j < 8; ++j) {
      float rj = (j < 4) ? r0[j] : r1[j - 4];
      v[j] = s[j] * inv + rj;
      m = fmaxf(m, v[j]);
    }
  }
#pragma unroll
  for (int o = 1; o <= 4; o <<= 1) m = fmaxf(m, __shfl_xor(m, o, 64));
  float ex = 0.f;
  if (q < 5) {
#pragma unroll
    for (int j = 0; j < 8; ++j) ex += __expf(v[j] - m);
  }
#pragma unroll
  for (int o = 1; o <= 4; o <<= 1) ex += __shfl_xor(ex, o, 64);
  float ls = __logf(ex) + m;

  if (g == 0 && q < 5) {
    float* op = out + (size_t)node * OUT_DIM + q * 8;
    f32x4 o0, o1;
#pragma unroll
    for (int j = 0; j < 4; ++j) { o0[j] = v[j] - ls; o1[j] = v[j + 4] - ls; }
    *(f32x4*)op = o0;
    *(f32x4*)(op + 4) = o1;
  }
}

extern "C" void kernel_launch(void* const* d_in, const int* in_sizes, int n_in,
                              void* d_out, int out_size, void* d_ws, size_t ws_size,
                              hipStream_t stream) {
  const float* x   = (const float*)d_in[0];
  const int*   ei  = (const int*)d_in[1];
  const float* W1l = (const float*)d_in[2];
  const float* W1r = (const float*)d_in[3];
  const float* b1  = (const float*)d_in[4];
  const float* W2l = (const float*)d_in[5];
  const float* W2r = (const float*)d_in[6];
  const float* b2  = (const float*)d_in[7];
  float* out = (float*)d_out;

  const int* src = ei;
  const int* dst = ei + N_EDGES;

  char* ws = (char*)d_ws;
  int*      row_ptr = (int*)(ws + OFF_RP);
  int*      esrc    = (int*)(ws + OFF_ESRC);
  unsigned* stage   = (unsigned*)(ws + OFF_STAGE);
  int*      hist_g  = (int*)(ws + OFF_HISTG);
  int*      pfx_g   = (int*)(ws + OFF_PFXG);
  int*      btot    = (int*)(ws + OFF_BTOT);
  int*      bbase   = (int*)(ws + OFF_BBASE);
  char*     ABb     = ws + OFF_AB;
  unsigned short* Wt1 = (unsigned short*)(ws + OFF_W1T);
  unsigned short* Wt2 = (unsigned short*)(ws + OFF_W2T);
  unsigned short* P2  = (unsigned short*)(ws + OFF_P2);
  float* R2 = (float*)(ws + OFF_R2);

  k_conv<<<CONVX_BLOCKS + 337, 256, 0, stream>>>(x, ABb, W1l, W1r, W2l, W2r,
                                                 Wt1, Wt2);

  k_hist<<<BINA_BLOCKS, 1024, 0, stream>>>(dst, hist_g);
  k_hscanA<<<(NBUCKETS + 3) / 4, 256, 0, stream>>>(hist_g, pfx_g, btot);
  k_hscanB<<<1, 1024, 0, stream>>>(btot, bbase, row_ptr);
  k_fill2<<<BINA_BLOCKS, 1024, 0, stream>>>(src, dst, bbase, pfx_g, stage);
  k_bsort<<<NBUCKETS, 256, 0, stream>>>(stage, bbase, row_ptr, esrc);

  k_agg1<<<N_NODES / 4, 256, 0, stream>>>(ABb, row_ptr, esrc);
  k_gemm<<<M_PAD / 64, 512, 0, stream>>>(ABb, (const short*)Wt1,
                                         (const short*)Wt2, b1, b2, P2, R2);
  k_agg2<<<N_NODES / 4, 256, 0, stream>>>(P2, R2, row_ptr, esrc, out);
}

// Round 14
// 208.168 us; speedup vs baseline: 2.1613x; 1.0070x over previous
//
#include <hip/hip_runtime.h>
#include <hip/hip_bf16.h>

#define N_NODES 50000
#define N_EDGES 800000
#define IN_DIM 128
#define HID_DIM 256
#define OUT_DIM 40
#define M_PAD 50048      // 782 * 64
#define NBUCKETS 782     // 64 nodes per bucket
#define EPB 8192         // edges per binning block
#define BINA_BLOCKS 98   // ceil(800000/8192)
#define BLK_PAD 128      // per-bucket block-count row, padded
#define CONVX_BLOCKS 3125

// ---- workspace layout (bytes), 16-B aligned ----
#define OFF_RP     0         // 50001 int
#define OFF_ESRC   200064    // 800000 int
#define OFF_STAGE  3400064   // 800000 u32
#define OFF_HISTG  6600064   // 782*128 int
#define OFF_PFXG   7000448   // 782*128 int
#define OFF_BTOT   7400832   // 782 int
#define OFF_BBASE  7403968   // 783 int
#define OFF_AB     7407104   // M_PAD x 256 bf16
#define OFF_W1T    33031680  // 256 x 256 bf16
#define OFF_W2T    33162752  // 80 x 256 bf16
#define OFF_P2     33203712  // M_PAD x 40 bf16
#define OFF_R2     37207552  // M_PAD x 40 f32
// end 45215232 (~45 MB)

typedef __attribute__((ext_vector_type(8))) short short8;
typedef __attribute__((ext_vector_type(4))) float f32x4;

__device__ __forceinline__ float bfu2f(unsigned u) {
  union { unsigned i; float f; } c; c.i = u << 16; return c.f;
}
__device__ __forceinline__ unsigned f2bfu(float f) {
  union { float f; unsigned i; } c; c.f = f;
  return (c.i + 0x7fffu + ((c.i >> 16) & 1u)) >> 16;   // RNE
}

#define GLOAD_LDS16(g, l)                                                      \
  __builtin_amdgcn_global_load_lds(                                            \
      (const __attribute__((address_space(1))) void*)(g),                      \
      (__attribute__((address_space(3))) void*)(l), 16, 0, 0)

// ---------------- CSR build (atomic-free deterministic bucket sort) ---------
__global__ __launch_bounds__(1024) void k_hist(const int* __restrict__ dst,
                                               int* __restrict__ hist_g) {
  __shared__ int hist[NBUCKETS];
  int t = threadIdx.x, blk = blockIdx.x;
  for (int b = t; b < NBUCKETS; b += 1024) hist[b] = 0;
  __syncthreads();
  int e0 = blk * EPB, e1 = min(e0 + EPB, N_EDGES);
  for (int e = e0 + t; e < e1; e += 1024) atomicAdd(&hist[dst[e] >> 6], 1);
  __syncthreads();
  for (int b = t; b < NBUCKETS; b += 1024) hist_g[b * BLK_PAD + blk] = hist[b];
}

__global__ __launch_bounds__(256) void k_hscanA(const int* __restrict__ hist_g,
                                                int* __restrict__ pfx_g,
                                                int* __restrict__ btot) {
  int wave = blockIdx.x * 4 + (threadIdx.x >> 6);
  int lane = threadIdx.x & 63;
  if (wave >= NBUCKETS) return;
  const int* h = hist_g + wave * BLK_PAD;
  int v0 = (lane < BINA_BLOCKS) ? h[lane] : 0;
  int v1 = (lane + 64 < BINA_BLOCKS) ? h[lane + 64] : 0;
  int s0 = v0;
#pragma unroll
  for (int d = 1; d < 64; d <<= 1) {
    int u = __shfl_up(s0, d, 64);
    if (lane >= d) s0 += u;
  }
  int tot0 = __shfl(s0, 63, 64);
  int s1 = v1;
#pragma unroll
  for (int d = 1; d < 64; d <<= 1) {
    int u = __shfl_up(s1, d, 64);
    if (lane >= d) s1 += u;
  }
  s1 += tot0;
  pfx_g[wave * BLK_PAD + lane] = s0 - v0;
  if (lane + 64 < BLK_PAD) pfx_g[wave * BLK_PAD + lane + 64] = s1 - v1;
  if (lane == 63) btot[wave] = s1;
}

__global__ __launch_bounds__(1024) void k_hscanB(const int* __restrict__ btot,
                                                 int* __restrict__ bbase,
                                                 int* __restrict__ row_ptr) {
  __shared__ int part[1024];
  int t = threadIdx.x;
  int v = (t < NBUCKETS) ? btot[t] : 0;
  part[t] = v;
  __syncthreads();
  for (int off = 1; off < 1024; off <<= 1) {
    int u = (t >= off) ? part[t - off] : 0;
    __syncthreads();
    part[t] += u;
    __syncthreads();
  }
  if (t < NBUCKETS) bbase[t] = part[t] - v;
  if (t == NBUCKETS - 1) {
    bbase[NBUCKETS] = part[t];
    row_ptr[N_NODES] = part[t];
  }
}

__global__ __launch_bounds__(1024) void k_fill2(const int* __restrict__ src,
                                                const int* __restrict__ dst,
                                                const int* __restrict__ bbase,
                                                const int* __restrict__ pfx_g,
                                                unsigned* __restrict__ stage) {
  __shared__ int cur[NBUCKETS];
  int t = threadIdx.x, blk = blockIdx.x;
  for (int b = t; b < NBUCKETS; b += 1024)
    cur[b] = bbase[b] + pfx_g[b * BLK_PAD + blk];
  __syncthreads();
  int e0 = blk * EPB, e1 = min(e0 + EPB, N_EDGES);
  for (int e = e0 + t; e < e1; e += 1024) {
    int d = dst[e];
    int pos = atomicAdd(&cur[d >> 6], 1);
    stage[pos] = ((unsigned)src[e] << 6) | (unsigned)(d & 63);
  }
}

__global__ __launch_bounds__(256) void k_bsort(const unsigned* __restrict__ stage,
                                               const int* __restrict__ bbase,
                                               int* __restrict__ row_ptr,
                                               int* __restrict__ esrc) {
  __shared__ int lcnt[64];
  __shared__ int lout[1536];
  int b = blockIdx.x, t = threadIdx.x;
  int base = bbase[b];
  int nb = bbase[b + 1] - base;
  if (t < 64) lcnt[t] = 0;
  __syncthreads();
  const unsigned* sp = stage + base;
  for (int e = t; e < nb; e += 256) atomicAdd(&lcnt[sp[e] & 63u], 1);
  __syncthreads();
  if (t < 64) {
    int v = lcnt[t];
    int s = v;
#pragma unroll
    for (int d = 1; d < 64; d <<= 1) {
      int u = __shfl_up(s, d, 64);
      if (t >= d) s += u;
    }
    int node = b * 64 + t;
    if (node < N_NODES) row_ptr[node] = base + s - v;
    lcnt[t] = s - v;
  }
  __syncthreads();
  for (int e = t; e < nb; e += 256) {
    unsigned p = sp[e];
    int lp = atomicAdd(&lcnt[p & 63u], 1);
    lout[lp] = (int)(p >> 6);
  }
  __syncthreads();
  for (int i = t; i < nb; i += 256) esrc[base + i] = lout[i];
}

// ---------------- conversions + pad-zero (merged) ----------------
__global__ __launch_bounds__(256) void k_conv(const float* __restrict__ x,
                                              char* __restrict__ ABb,
                                              const float* __restrict__ W1l,
                                              const float* __restrict__ W1r,
                                              const float* __restrict__ W2l,
                                              const float* __restrict__ W2r,
                                              unsigned short* __restrict__ Wt1,
                                              unsigned short* __restrict__ Wt2) {
  if (blockIdx.x < CONVX_BLOCKS) {
    int t = blockIdx.x * 256 + threadIdx.x;
    int row = t >> 4, c8 = (t & 15) << 3;
    const float* xp = x + (size_t)row * IN_DIM + c8;
    unsigned short o[8];
#pragma unroll
    for (int i = 0; i < 8; ++i) o[i] = (unsigned short)f2bfu(xp[i]);
    *(short8*)(ABb + (size_t)row * 512 + 256 + c8 * 2) = *(short8*)o;
  } else if (blockIdx.x < CONVX_BLOCKS + 256) {
    int n = blockIdx.x - CONVX_BLOCKS;
    int k = threadIdx.x;
    float v = (k < 128) ? W1l[(size_t)k * HID_DIM + n]
                        : W1r[(size_t)(k - 128) * HID_DIM + n];
    Wt1[(size_t)n * 256 + k] = (unsigned short)f2bfu(v);
  } else if (blockIdx.x < CONVX_BLOCKS + 336) {
    int n = blockIdx.x - CONVX_BLOCKS - 256;
    int k = threadIdx.x;
    float v = (n < OUT_DIM) ? W2l[(size_t)k * OUT_DIM + n]
                            : W2r[(size_t)k * OUT_DIM + (n - OUT_DIM)];
    Wt2[(size_t)n * 256 + k] = (unsigned short)f2bfu(v);
  } else {
    char* pad = ABb + (size_t)N_NODES * 512;
    f32x4 z = (f32x4){0.f, 0.f, 0.f, 0.f};
#pragma unroll
    for (int i = 0; i < 6; ++i)
      *(f32x4*)(pad + (threadIdx.x * 6 + i) * 16) = z;
  }
}

// ---------------- aggregation 1 (bf16 gather, mean, 2x unrolled) ------------
__global__ __launch_bounds__(256) void k_agg1(char* __restrict__ ABb,
    const int* __restrict__ row_ptr, const int* __restrict__ esrc) {
  int tid = threadIdx.x;
  int node = blockIdx.x * 4 + (tid >> 6);
  int lane = tid & 63;
  int g = lane >> 4;
  int q = lane & 15;
  int beg = row_ptr[node], end = row_ptr[node + 1];
  float s[8];
#pragma unroll
  for (int j = 0; j < 8; ++j) s[j] = 0.f;

  for (int e0 = beg; e0 < end; e0 += 8) {
    int eA = e0 + g;
    int eB = eA + 4;
    int iA = min(eA, end - 1);
    int iB = min(eB, end - 1);
    int sA = esrc[iA], sB = esrc[iB];
    float wA = (eA < end) ? 1.f : 0.f;
    float wB = (eB < end) ? 1.f : 0.f;
    short8 vA = *(const short8*)(ABb + (size_t)sA * 512 + 256 + q * 16);
    short8 vB = *(const short8*)(ABb + (size_t)sB * 512 + 256 + q * 16);
#pragma unroll
    for (int j = 0; j < 8; ++j)
      s[j] = fmaf(wA, bfu2f((unsigned short)vA[j]), s[j]);
#pragma unroll
    for (int j = 0; j < 8; ++j)
      s[j] = fmaf(wB, bfu2f((unsigned short)vB[j]), s[j]);
  }
#pragma unroll
  for (int j = 0; j < 8; ++j) {
    s[j] += __shfl_xor(s[j], 16, 64);
    s[j] += __shfl_xor(s[j], 32, 64);
  }
  float inv = 1.0f / (float)max(end - beg, 1);
  if (lane < 16) {
    unsigned short o[8];
#pragma unroll
    for (int j = 0; j < 8; ++j) o[j] = (unsigned short)f2bfu(s[j] * inv);
    *(short8*)(ABb + (size_t)node * 512 + q * 16) = *(short8*)o;
  }
}

// ---------------- fused GEMM (8 waves, weight-prefetch ILP) ----------------
__global__ __launch_bounds__(512) void k_gemm(
    const char* __restrict__ ABb, const short* __restrict__ Wt1,
    const short* __restrict__ Wt2, const float* __restrict__ b1,
    const float* __restrict__ b2, unsigned short* __restrict__ P2,
    float* __restrict__ R2) {
  __shared__ __align__(16) char As[64 * 512];
  const int tid = threadIdx.x;
  const int w = tid >> 6, lane = tid & 63;
  const int row0 = blockIdx.x * 64;

  {  // stage AB tile: swizzled source -> linear LDS (4 rounds x 8KB)
    const char* gbase = ABb + (size_t)row0 * 512;
#pragma unroll
    for (int i = 0; i < 4; ++i) {
      int o = i * 8192 + w * 1024 + lane * 16;
      int row = o >> 9;
      int kslot = ((o & 511) >> 4) ^ (row & 7);
      GLOAD_LDS16(gbase + row * 512 + kslot * 16, As + i * 8192 + w * 1024);
    }
  }

  // prefetch ALL phase-1 weights while staging drains (16 x 16B, independent)
  const short* wb1 = Wt1 + (size_t)(w * 32 + (lane & 15)) * 256 + (lane >> 4) * 8;
  short8 wf1[8][2];
#pragma unroll
  for (int ks = 0; ks < 8; ++ks)
#pragma unroll
    for (int ni = 0; ni < 2; ++ni)
      wf1[ks][ni] = *(const short8*)(wb1 + ni * 16 * 256 + ks * 32);

  __syncthreads();

  // ---- phase 1: layer-1 MFMAs; wave w -> cols w*32..+31 ----
  f32x4 acc[4][2];
#pragma unroll
  for (int mi = 0; mi < 4; ++mi)
#pragma unroll
    for (int ni = 0; ni < 2; ++ni) acc[mi][ni] = (f32x4){0.f, 0.f, 0.f, 0.f};

#pragma unroll
  for (int ks = 0; ks < 8; ++ks) {
    short8 af[4];
#pragma unroll
    for (int mi = 0; mi < 4; ++mi) {
      int row = mi * 16 + (lane & 15);
      int kslot = (ks * 4 + (lane >> 4)) ^ (row & 7);
      af[mi] = *(const short8*)(As + row * 512 + kslot * 16);
    }
#pragma unroll
    for (int mi = 0; mi < 4; ++mi)
#pragma unroll
      for (int ni = 0; ni < 2; ++ni)
        acc[mi][ni] = __builtin_amdgcn_mfma_f32_16x16x32_bf16(
            af[mi], wf1[ks][ni], acc[mi][ni], 0, 0, 0);
  }

  __syncthreads();   // all waves done READING As

  // ---- epilogue 1: H = relu(acc + b1) -> LDS bf16 (write-side swizzle) ----
#pragma unroll
  for (int ni = 0; ni < 2; ++ni) {
    int col = w * 32 + ni * 16 + (lane & 15);
    float bv = b1[col];
#pragma unroll
    for (int mi = 0; mi < 4; ++mi) {
#pragma unroll
      for (int r = 0; r < 4; ++r) {
        int row = mi * 16 + (lane >> 4) * 4 + r;
        float v = fmaxf(acc[mi][ni][r] + bv, 0.f);
        int gr = (col >> 3) ^ (row & 7);
        *(unsigned short*)(As + row * 512 + gr * 16 + (col & 7) * 2) =
            (unsigned short)f2bfu(v);
      }
    }
  }
  __syncthreads();

  // ---- phase 2: wave w -> rowtile rt=w>>1; cols: even w ni 0..2, odd 3..4 --
  const int rt = w >> 1;
  const int ni0 = (w & 1) ? 3 : 0;
  const int nin = (w & 1) ? 2 : 3;
  f32x4 acc2[3];
#pragma unroll
  for (int i = 0; i < 3; ++i) acc2[i] = (f32x4){0.f, 0.f, 0.f, 0.f};

  const short* wb2 = Wt2 + (size_t)(lane & 15) * 256 + (lane >> 4) * 8;
  const int arow = rt * 16 + (lane & 15);

  // 2-deep static pipeline over ks (all indices compile-time)
  short8 wf2[2][3];
#pragma unroll
  for (int i = 0; i < 3; ++i)
    wf2[0][i] = *(const short8*)(wb2 + min(ni0 + i, 4) * 16 * 256);

#pragma unroll
  for (int ks = 0; ks < 8; ++ks) {
    if (ks < 7) {
#pragma unroll
      for (int i = 0; i < 3; ++i)
        wf2[(ks + 1) & 1][i] =
            *(const short8*)(wb2 + min(ni0 + i, 4) * 16 * 256 + (ks + 1) * 32);
    }
    int kslot = (ks * 4 + (lane >> 4)) ^ (arow & 7);
    short8 a = *(const short8*)(As + arow * 512 + kslot * 16);
#pragma unroll
    for (int i = 0; i < 3; ++i) {
      if (i < nin)
        acc2[i] = __builtin_amdgcn_mfma_f32_16x16x32_bf16(
            a, wf2[ks & 1][i], acc2[i], 0, 0, 0);
    }
  }

  __syncthreads();   // done reading As (H)

  // ---- epilogue 2: acc2 -> LDS staging; coalesced global writes ----
  for (int i = 0; i < 3; ++i) {
    if (i < nin) {
      int col = (ni0 + i) * 16 + (lane & 15);
#pragma unroll
      for (int r = 0; r < 4; ++r) {
        int row = rt * 16 + (lane >> 4) * 4 + r;
        float v = acc2[i][r];
        if (col < OUT_DIM) {
          *(unsigned short*)(As + row * 80 + col * 2) = (unsigned short)f2bfu(v);
        } else {
          *(float*)(As + 5120 + row * 160 + (col - OUT_DIM) * 4) =
              v + b2[col - OUT_DIM];
        }
      }
    }
  }
  __syncthreads();

  {  // P2: 5120B contiguous; R2: 10240B contiguous
    char* p2g = (char*)P2 + (size_t)row0 * 80;
    if (tid < 320) *(f32x4*)(p2g + tid * 16) = *(const f32x4*)(As + tid * 16);
    char* r2g = (char*)R2 + (size_t)row0 * 160;
    for (int i = tid; i < 640; i += 512)
      *(f32x4*)(r2g + i * 16) = *(const f32x4*)(As + 5120 + i * 16);
  }
}

// ---------------- agg2 + log_softmax ----------------
__global__ __launch_bounds__(256) void k_agg2(const unsigned short* __restrict__ P2,
    const float* __restrict__ R2, const int* __restrict__ row_ptr,
    const int* __restrict__ esrc, float* __restrict__ out) {
  int tid = threadIdx.x;
  int node = blockIdx.x * 4 + (tid >> 6);
  int lane = tid & 63;
  int g = lane >> 3;
  int q = lane & 7;
  int beg = row_ptr[node], end = row_ptr[node + 1];
  float s[8];
#pragma unroll
  for (int j = 0; j < 8; ++j) s[j] = 0.f;

  for (int e0 = beg; e0 < end; e0 += 8) {
    int e = e0 + g;
    if (e < end && q < 5) {
      int srcn = esrc[e];
      short8 v = *(const short8*)((const char*)P2 + (size_t)srcn * 80 + q * 16);
#pragma unroll
      for (int j = 0; j < 8; ++j)
        s[j] += bfu2f((unsigned short)v[j]);
    }
  }
#pragma unroll
  for (int j = 0; j < 8; ++j) {
    s[j] += __shfl_xor(s[j], 8, 64);
    s[j] += __shfl_xor(s[j], 16, 64);
    s[j] += __shfl_xor(s[j], 32, 64);
  }

  float inv = 1.0f / (float)max(end - beg, 1);
  float v[8];
  float m = -1e30f;
  if (q < 5) {
    const float* rr = R2 + (size_t)node * OUT_DIM + q * 8;
    f32x4 r0 = *(const f32x4*)rr;
    f32x4 r1 = *(const f32x4*)(rr + 4);
#pragma unroll
    for (int j = 0; j < 8; ++j) {
      float rj = (j < 4) ? r0[j] : r1[j - 4];
      v[j] = s[j] * inv + rj;
      m = fmaxf(m, v[j]);
    }
  }
#pragma unroll
  for (int o = 1; o <= 4; o <<= 1) m = fmaxf(m, __shfl_xor(m, o, 64));
  float ex = 0.f;
  if (q < 5) {
#pragma unroll
    for (int j = 0; j < 8; ++j) ex += __expf(v[j] - m);
  }
#pragma unroll
  for (int o = 1; o <= 4; o <<= 1) ex += __shfl_xor(ex, o, 64);
  float ls = __logf(ex) + m;

  if (g == 0 && q < 5) {
    float* op = out + (size_t)node * OUT_DIM + q * 8;
    f32x4 o0, o1;
#pragma unroll
    for (int j = 0; j < 4; ++j) { o0[j] = v[j] - ls; o1[j] = v[j + 4] - ls; }
    *(f32x4*)op = o0;
    *(f32x4*)(op + 4) = o1;
  }
}

extern "C" void kernel_launch(void* const* d_in, const int* in_sizes, int n_in,
                              void* d_out, int out_size, void* d_ws, size_t ws_size,
                              hipStream_t stream) {
  const float* x   = (const float*)d_in[0];
  const int*   ei  = (const int*)d_in[1];
  const float* W1l = (const float*)d_in[2];
  const float* W1r = (const float*)d_in[3];
  const float* b1  = (const float*)d_in[4];
  const float* W2l = (const float*)d_in[5];
  const float* W2r = (const float*)d_in[6];
  const float* b2  = (const float*)d_in[7];
  float* out = (float*)d_out;

  const int* src = ei;
  const int* dst = ei + N_EDGES;

  char* ws = (char*)d_ws;
  int*      row_ptr = (int*)(ws + OFF_RP);
  int*      esrc    = (int*)(ws + OFF_ESRC);
  unsigned* stage   = (unsigned*)(ws + OFF_STAGE);
  int*      hist_g  = (int*)(ws + OFF_HISTG);
  int*      pfx_g   = (int*)(ws + OFF_PFXG);
  int*      btot    = (int*)(ws + OFF_BTOT);
  int*      bbase   = (int*)(ws + OFF_BBASE);
  char*     ABb     = ws + OFF_AB;
  unsigned short* Wt1 = (unsigned short*)(ws + OFF_W1T);
  unsigned short* Wt2 = (unsigned short*)(ws + OFF_W2T);
  unsigned short* P2  = (unsigned short*)(ws + OFF_P2);
  float* R2 = (float*)(ws + OFF_R2);

  k_conv<<<CONVX_BLOCKS + 337, 256, 0, stream>>>(x, ABb, W1l, W1r, W2l, W2r,
                                                 Wt1, Wt2);

  k_hist<<<BINA_BLOCKS, 1024, 0, stream>>>(dst, hist_g);
  k_hscanA<<<(NBUCKETS + 3) / 4, 256, 0, stream>>>(hist_g, pfx_g, btot);
  k_hscanB<<<1, 1024, 0, stream>>>(btot, bbase, row_ptr);
  k_fill2<<<BINA_BLOCKS, 1024, 0, stream>>>(src, dst, bbase, pfx_g, stage);
  k_bsort<<<NBUCKETS, 256, 0, stream>>>(stage, bbase, row_ptr, esrc);

  k_agg1<<<N_NODES / 4, 256, 0, stream>>>(ABb, row_ptr, esrc);
  k_gemm<<<M_PAD / 64, 512, 0, stream>>>(ABb, (const short*)Wt1,
                                         (const short*)Wt2, b1, b2, P2, R2);
  k_agg2<<<N_NODES / 4, 256, 0, stream>>>(P2, R2, row_ptr, esrc, out);
}